// Round 2
// baseline (364.020 us; speedup 1.0000x reference)
//
#include <hip/hip_runtime.h>
#include <math.h>

#define LSEQ   8192
#define CHUNK  64
#define NCHUNK 128
#define NBATCH 2048

// ws float layout:
//   [0]        v (NBATCH*NCHUNK*64 = 16777216 floats)
//   [T0]       tables: P, A1, K, Wh(bf16), Wl(bf16)
#define WS_V   0
#define T0     (NBATCH * NCHUNK * 64)
#define WS_P   (T0)
#define WS_A1  (T0 + 4096)
#define WS_K   (T0 + 8192)
#define WS_WH  (T0 + 8256)    /* 4096 floats = 8192 bf16: W hi, row-major 128x64 */
#define WS_WL  (T0 + 12352)   /* 4096 floats: W lo */

typedef short bf16x8 __attribute__((ext_vector_type(8)));
typedef float f32x4  __attribute__((ext_vector_type(4)));

__device__ __forceinline__ float rl(float v, int l) {
  return __builtin_bit_cast(float,
      __builtin_amdgcn_readlane(__builtin_bit_cast(int, v), l));
}

__device__ __forceinline__ unsigned short bf16rne(float x) {
  unsigned b = __builtin_bit_cast(unsigned, x);
  return (unsigned short)((b + 0x7fffu + ((b >> 16) & 1u)) >> 16);
}
__device__ __forceinline__ void split2(float x, unsigned short& h, unsigned short& l) {
  h = bf16rne(x);
  float hf = __builtin_bit_cast(float, ((unsigned)h) << 16);
  l = bf16rne(x - hf);
}

// ---------------- pre: readlane-based 64x64 matmul, 1024 thr = 16 waves --------
// O[i][c] (+= I/S1/S2) = sum_m A[i - aShift][m] * B[m][c - bShift]
// stored only for i in [rLo,rHi), c in [cLo,cHi). Row-major stride 64 LDS.
// Lane = c; wave w owns rows 4w..4w+3 (16 waves -> 4 waves/SIMD for latency
// hiding). doSync: barrier at entry; within one block-doubling step the three
// matmuls write disjoint regions and read only prior-step state, so only the
// first needs the barrier. Waves whose rows lie fully outside [rLo,rHi) skip.
__device__ __forceinline__ void mm_rl(
    float* __restrict__ dst, const float* __restrict__ Abuf,
    const float* __restrict__ Bbuf, const float* __restrict__ S1,
    const float* __restrict__ S2, int addI,
    int aShift, int bShift, int rLo, int rHi, int cLo, int cHi, int doSync) {
  if (doSync) __syncthreads();   // prior step's stores visible; prior reads done
  const int lane = threadIdx.x & 63;
  const int rb   = (threadIdx.x >> 6) << 2;        // 4 rows per wave
  if (rb >= rHi || rb + 4 <= rLo) return;          // whole wave out of range
  int bi = lane - bShift;
  bi = bi < 0 ? 0 : (bi > 63 ? 63 : bi);

  float a[4];
#pragma unroll
  for (int j = 0; j < 4; ++j) {
    int r = rb + j - aShift;
    r = r < 0 ? 0 : (r > 63 ? 63 : r);
    a[j] = Abuf[r * 64 + lane];     // lane m of this wave holds A[r][m]
  }
  float o[4] = {0.f, 0.f, 0.f, 0.f};

#pragma unroll 16
  for (int m = 0; m < 64; ++m) {
    float bv = Bbuf[m * 64 + bi];
#pragma unroll
    for (int j = 0; j < 4; ++j)
      o[j] += rl(a[j], m) * bv;     // readlane: uniform SGPR lane index
  }

#pragma unroll
  for (int j = 0; j < 4; ++j) {
    const int i = rb + j;
    float v = o[j];
    if (addI && i == lane) v += 1.f;
    if (S1) v += S1[i * 64 + lane];
    if (S2) v += S2[i * 64 + lane];
    if (i >= rLo && i < rHi && lane >= cLo && lane < cHi)
      dst[i * 64 + lane] = v;
  }
}

// Precompute (single workgroup, 1024 threads):
// X=hA; BL=(I+X4)(I+X2)(I+X) ~= (I-X)^-1 (err ~1e-8); Ab=BL(I+X); Bb=step*BL@B;
// block-doubled A1 rows / gB cols; P=Ab^64; K; W=[Kmat+D*I;Brev] bf16 hi/lo.
__global__ void __launch_bounds__(1024)
ssm_pre(const float* __restrict__ Ag, const float* __restrict__ Bg,
        const float* __restrict__ Cg, const float* __restrict__ Dg,
        const float* __restrict__ lsg, float* __restrict__ ws) {
  __shared__ float LDS[7 * 4096 + 64];
  float* L0  = LDS;
  float* L1  = LDS + 4096;
  float* L2  = LDS + 2 * 4096;
  float* L3  = LDS + 3 * 4096;
  float* L4  = LDS + 4 * 4096;
  float* gBl = LDS + 5 * 4096;   // gB[m][j] = (Ab^j Bb)[m], row-major
  float* A1l = LDS + 6 * 4096;   // A1 row i = C*Ab^(i+1)
  float* Kl  = LDS + 7 * 4096;

  const int t = threadIdx.x;
  const float step = expf(lsg[0]);
  const float h = 0.5f * step;
  const float D0 = Dg[0];

  // X = h*A
  for (int i = t; i < 4096; i += 1024) L0[i] = h * Ag[i];

  mm_rl(L1, L0, L0, nullptr, nullptr, 0, 0, 0, 0, 64, 0, 64, 1);   // X2
  mm_rl(L2, L1, L1, nullptr, nullptr, 0, 0, 0, 0, 64, 0, 64, 1);   // X4
  mm_rl(L3, L2, L1, L2, L1, 1, 0, 0, 0, 64, 0, 64, 1);             // T1=(I+X4)(I+X2)
  mm_rl(L4, L3, L0, L3, nullptr, 0, 0, 0, 0, 64, 0, 64, 1);        // BL=T1(I+X)
  mm_rl(L2, L4, L0, L4, nullptr, 0, 0, 0, 0, 64, 0, 64, 1);        // Ab=BL(I+X) -> L2
  __syncthreads();

  // Bb -> gB col 0 ; A1 row 0 = C@Ab
  if (t < 64) {
    float acc = 0.f, a1 = 0.f;
    for (int m = 0; m < 64; ++m) acc += L4[t * 64 + m] * Bg[m];
    gBl[t * 64] = step * acc;
    for (int m = 0; m < 64; ++m) a1 += Cg[m] * L2[m * 64 + t];
    A1l[t] = a1;
  }

  // Block-doubling: pw = Ab^k. Ext cols/rows [k,2k), then square.
  float* pw = L2;
  float* freebuf[4] = {L0, L1, L3, L4};
  int fi = 0;
  for (int k = 1; k <= 32; k <<= 1) {
    mm_rl(gBl, pw, gBl, nullptr, nullptr, 0, 0, k, 0, 64, k, 2 * k, 1);
    mm_rl(A1l, A1l, pw, nullptr, nullptr, 0, k, 0, k, 2 * k, 0, 64, 0);
    if (k < 32) {
      float* d = freebuf[fi]; fi = (fi + 1) & 3;
      mm_rl(d, pw, pw, nullptr, nullptr, 0, 0, 0, 0, 64, 0, 64, 0);
      pw = d;
    }
  }
  // P = Ab^64 -> L2 (Ab long dead)
  mm_rl(L2, pw, pw, nullptr, nullptr, 0, 0, 0, 0, 64, 0, 64, 1);
  __syncthreads();

  // K[r] = C . gB col r
  if (t < 64) {
    float acc = 0.f;
    for (int m = 0; m < 64; ++m) acc += Cg[m] * gBl[m * 64 + t];
    Kl[t] = acc;
  }
  __syncthreads();

  // Outputs
  float* wsP  = ws + WS_P;
  float* wsA1 = ws + WS_A1;
  for (int e = t; e < 4096; e += 1024) {
    wsP[e]  = L2[e];
    wsA1[e] = A1l[e];
  }
  unsigned short* wh = (unsigned short*)(ws + WS_WH);
  unsigned short* wl = (unsigned short*)(ws + WS_WL);
  for (int e = t; e < 8192; e += 1024) {
    int i = e >> 6, j = e & 63;
    float w;
    if (i < 64) w = ((i >= j) ? Kl[i - j] : 0.f) + ((i == j) ? D0 : 0.f);
    else        w = gBl[(i - 64) * 64 + (63 - j)];   // Brev[n][j]=(Ab^(63-j)Bb)[n]
    unsigned short hh, ll;
    split2(w, hh, ll);
    wh[e] = hh;
    wl[e] = ll;
  }
}

// Phase 1: [y0; v] = W @ U via MFMA bf16x2 (hi*hi + hi*lo + lo*hi, fp32 acc).
__global__ void __launch_bounds__(256, 2)
ssm_conv_mfma(const float* __restrict__ u, const float* __restrict__ ws,
              float* __restrict__ y, float* __restrict__ v) {
  const int lane = threadIdx.x & 63;
  const int n = lane & 15, quad = lane >> 4;
  const int wid = blockIdx.x * 4 + (threadIdx.x >> 6);

  const unsigned short* wh = (const unsigned short*)(ws + WS_WH);
  const unsigned short* wl = (const unsigned short*)(ws + WS_WL);

  bf16x8 ah[8][2], al[8][2];
#pragma unroll
  for (int t = 0; t < 8; ++t)
#pragma unroll
    for (int ks = 0; ks < 2; ++ks) {
      int off = (t * 16 + n) * 64 + ks * 32 + quad * 8;
      ah[t][ks] = *(const bf16x8*)(wh + off);
      al[t][ks] = *(const bf16x8*)(wl + off);
    }

#pragma unroll
  for (int g = 0; g < 4; ++g) {
    const int G = wid * 4 + g;
    const int row = G >> 3;
    const int c = ((G & 7) << 4) + n;
    const float* ub = u + (size_t)row * LSEQ + c * 64 + quad * 8;
    f32x4 f0 = *(const f32x4*)(ub);
    f32x4 f1 = *(const f32x4*)(ub + 4);
    f32x4 f2 = *(const f32x4*)(ub + 32);
    f32x4 f3 = *(const f32x4*)(ub + 36);

    bf16x8 bh0, bl0, bh1, bl1;
    {
      float xs0[8] = {f0[0], f0[1], f0[2], f0[3], f1[0], f1[1], f1[2], f1[3]};
      float xs1[8] = {f2[0], f2[1], f2[2], f2[3], f3[0], f3[1], f3[2], f3[3]};
#pragma unroll
      for (int j = 0; j < 8; ++j) {
        unsigned short hh, ll;
        split2(xs0[j], hh, ll);
        bh0[j] = (short)hh; bl0[j] = (short)ll;
        split2(xs1[j], hh, ll);
        bh1[j] = (short)hh; bl1[j] = (short)ll;
      }
    }

    float* ybase = y + (size_t)row * LSEQ + c * 64;
    float* vbase = v + ((size_t)row * NCHUNK + c) * 64;
#pragma unroll
    for (int t = 0; t < 8; ++t) {
      f32x4 acc = {0.f, 0.f, 0.f, 0.f};
      acc = __builtin_amdgcn_mfma_f32_16x16x32_bf16(ah[t][0], bh0, acc, 0, 0, 0);
      acc = __builtin_amdgcn_mfma_f32_16x16x32_bf16(ah[t][1], bh1, acc, 0, 0, 0);
      acc = __builtin_amdgcn_mfma_f32_16x16x32_bf16(ah[t][0], bl0, acc, 0, 0, 0);
      acc = __builtin_amdgcn_mfma_f32_16x16x32_bf16(ah[t][1], bl1, acc, 0, 0, 0);
      acc = __builtin_amdgcn_mfma_f32_16x16x32_bf16(al[t][0], bh0, acc, 0, 0, 0);
      acc = __builtin_amdgcn_mfma_f32_16x16x32_bf16(al[t][1], bh1, acc, 0, 0, 0);
      const int i0 = t * 16 + quad * 4;
      if (t < 4) *(f32x4*)(ybase + i0) = acc;
      else       *(f32x4*)(vbase + (i0 - 64)) = acc;
    }
  }
}

// Phase 2: MFMA batched scan. 16 batch-rows per wave; 1 wave/block; 128 blocks.
// State S is 64x16 (states x rows). Per chunk c:
//   accS = P@S + v_c        (4 M-tiles x 2 K-slabs x {hh,hl,lh} = 24 MFMA)
//   accY = y_conv_c + A1@S  (24 MFMA)  -> store y
// then S' (D-layout, 16 f32/lane) -> padded LDS -> B-fragment layout + hi/lo
// split for the next chunk. Fragment mappings identical to ssm_conv_mfma
// (A: lane holds M[mt*16+n][ks*32+q*8+j]; B: S[ks*32+q*8+j][n];
//  D: [mt*16+q*4+j][n]).
__global__ void __launch_bounds__(64)
ssm_scan_mfma(const float* __restrict__ ws, const float* __restrict__ v,
              float* __restrict__ y) {
  __shared__ float SL[16 * 68];   // [col n][68]: +4 pad -> conflict-free relayout
  const int lane = threadIdx.x & 63;
  const int n = lane & 15, q = lane >> 4;
  const int R = blockIdx.x * 16;

  const float* wsP  = ws + WS_P;
  const float* wsA1 = ws + WS_A1;

  // Static A-fragments for P and A1, hi/lo bf16.
  bf16x8 Ph[4][2], Pl[4][2], Ah[4][2], Al[4][2];
#pragma unroll
  for (int mt = 0; mt < 4; ++mt)
#pragma unroll
    for (int ks = 0; ks < 2; ++ks) {
      const float* pp = wsP  + (mt * 16 + n) * 64 + ks * 32 + q * 8;
      const float* aa = wsA1 + (mt * 16 + n) * 64 + ks * 32 + q * 8;
#pragma unroll
      for (int j = 0; j < 8; ++j) {
        unsigned short hh, ll;
        split2(pp[j], hh, ll);
        Ph[mt][ks][j] = (short)hh; Pl[mt][ks][j] = (short)ll;
        split2(aa[j], hh, ll);
        Ah[mt][ks][j] = (short)hh; Al[mt][ks][j] = (short)ll;
      }
    }

  // S B-fragments (zero-initialized: s_0 = 0)
  bf16x8 Sbh[2], Sbl[2];
#pragma unroll
  for (int ks = 0; ks < 2; ++ks)
#pragma unroll
    for (int j = 0; j < 8; ++j) { Sbh[ks][j] = 0; Sbl[ks][j] = 0; }

  // Per-lane global bases (row = R+n)
  const float* vrow = v + ((size_t)(R + n) * NCHUNK) * 64 + q * 4;
  float*       yrow = y + (size_t)(R + n) * LSEQ + q * 4;

  // Prefetch chunk 0
  f32x4 vc[4], yc[4];
#pragma unroll
  for (int mt = 0; mt < 4; ++mt) {
    vc[mt] = *(const f32x4*)(vrow + mt * 16);
    yc[mt] = *(const f32x4*)(yrow + mt * 16);
  }

  for (int c = 0; c < NCHUNK; ++c) {
    // Prefetch chunk c+1 (clamped; redundant on last iter)
    const int cn = (c + 1 < NCHUNK) ? (c + 1) : c;
    f32x4 vn[4], yn[4];
#pragma unroll
    for (int mt = 0; mt < 4; ++mt) {
      vn[mt] = *(const f32x4*)(vrow + (size_t)cn * 64 + mt * 16);
      yn[mt] = *(const f32x4*)(yrow + (size_t)cn * 64 + mt * 16);
    }

    // accS = P@S + v_c ; accY = y_c + A1@S   (S = s_old; zero frags at c=0)
    f32x4 accS[4], accY[4];
#pragma unroll
    for (int mt = 0; mt < 4; ++mt) {
      f32x4 as = vc[mt];
      as = __builtin_amdgcn_mfma_f32_16x16x32_bf16(Ph[mt][0], Sbh[0], as, 0, 0, 0);
      as = __builtin_amdgcn_mfma_f32_16x16x32_bf16(Ph[mt][1], Sbh[1], as, 0, 0, 0);
      as = __builtin_amdgcn_mfma_f32_16x16x32_bf16(Ph[mt][0], Sbl[0], as, 0, 0, 0);
      as = __builtin_amdgcn_mfma_f32_16x16x32_bf16(Ph[mt][1], Sbl[1], as, 0, 0, 0);
      as = __builtin_amdgcn_mfma_f32_16x16x32_bf16(Pl[mt][0], Sbh[0], as, 0, 0, 0);
      as = __builtin_amdgcn_mfma_f32_16x16x32_bf16(Pl[mt][1], Sbh[1], as, 0, 0, 0);
      accS[mt] = as;
      f32x4 ay = yc[mt];
      ay = __builtin_amdgcn_mfma_f32_16x16x32_bf16(Ah[mt][0], Sbh[0], ay, 0, 0, 0);
      ay = __builtin_amdgcn_mfma_f32_16x16x32_bf16(Ah[mt][1], Sbh[1], ay, 0, 0, 0);
      ay = __builtin_amdgcn_mfma_f32_16x16x32_bf16(Ah[mt][0], Sbl[0], ay, 0, 0, 0);
      ay = __builtin_amdgcn_mfma_f32_16x16x32_bf16(Ah[mt][1], Sbl[1], ay, 0, 0, 0);
      ay = __builtin_amdgcn_mfma_f32_16x16x32_bf16(Al[mt][0], Sbh[0], ay, 0, 0, 0);
      ay = __builtin_amdgcn_mfma_f32_16x16x32_bf16(Al[mt][1], Sbh[1], ay, 0, 0, 0);
      accY[mt] = ay;
    }

    // Store y for this chunk
#pragma unroll
    for (int mt = 0; mt < 4; ++mt)
      *(f32x4*)(yrow + (size_t)c * 64 + mt * 16) = accY[mt];

    // Relayout S' -> B-fragments via LDS (skip after last chunk)
    if (c + 1 < NCHUNK) {
      __syncthreads();   // single wave: near-free; orders prior reads vs writes
#pragma unroll
      for (int mt = 0; mt < 4; ++mt)
        *(f32x4*)(&SL[n * 68 + mt * 16 + q * 4]) = accS[mt];
      __syncthreads();
#pragma unroll
      for (int ks = 0; ks < 2; ++ks) {
        f32x4 s0 = *(const f32x4*)(&SL[n * 68 + ks * 32 + q * 8]);
        f32x4 s1 = *(const f32x4*)(&SL[n * 68 + ks * 32 + q * 8 + 4]);
#pragma unroll
        for (int j = 0; j < 4; ++j) {
          unsigned short hh, ll;
          split2(s0[j], hh, ll);
          Sbh[ks][j] = (short)hh; Sbl[ks][j] = (short)ll;
          split2(s1[j], hh, ll);
          Sbh[ks][j + 4] = (short)hh; Sbl[ks][j + 4] = (short)ll;
        }
      }
    }

    vc[0] = vn[0]; vc[1] = vn[1]; vc[2] = vn[2]; vc[3] = vn[3];
    yc[0] = yn[0]; yc[1] = yn[1]; yc[2] = yn[2]; yc[3] = yn[3];
  }
}

extern "C" void kernel_launch(void* const* d_in, const int* in_sizes, int n_in,
                              void* d_out, int out_size, void* d_ws, size_t ws_size,
                              hipStream_t stream) {
  const float* u  = (const float*)d_in[0];
  const float* A  = (const float*)d_in[1];
  const float* B  = (const float*)d_in[2];
  const float* C  = (const float*)d_in[3];
  const float* D  = (const float*)d_in[4];
  const float* ls = (const float*)d_in[5];
  float* ws  = (float*)d_ws;
  float* out = (float*)d_out;
  float* v   = ws + WS_V;

  ssm_pre<<<dim3(1), dim3(1024), 0, stream>>>(A, B, C, D, ls, ws);
  ssm_conv_mfma<<<dim3(1024), dim3(256), 0, stream>>>(u, ws, out, v);
  ssm_scan_mfma<<<dim3(NBATCH / 16), dim3(64), 0, stream>>>(ws, v, out);
}

// Round 3
// 337.121 us; speedup vs baseline: 1.0798x; 1.0798x over previous
//
#include <hip/hip_runtime.h>
#include <math.h>

#define LSEQ   8192
#define CHUNK  64
#define NCHUNK 128
#define NBATCH 2048
#define NGRP   16      /* superchunks */
#define GLEN   8       /* chunks per superchunk: NGRP*GLEN == NCHUNK */

// ws float layout:
//   [0]        v (NBATCH*NCHUNK*64 = 16777216 floats)
//   [T0]       tables, then E (2M floats), then SG (2M floats)
#define WS_V   0
#define T0     (NBATCH * NCHUNK * 64)
#define WS_P   (T0)
#define WS_A1  (T0 + 4096)
#define WS_K   (T0 + 8192)
#define WS_WH  (T0 + 8256)    /* 4096 floats = 8192 bf16: W hi, row-major 128x64 */
#define WS_WL  (T0 + 12352)   /* 4096 floats: W lo */
#define WS_PH  (T0 + 16448)   /* 2048 floats = 4096 bf16: P hi, row-major 64x64 */
#define WS_PL  (T0 + 18496)
#define WS_A1H (T0 + 20544)
#define WS_A1L (T0 + 22592)
#define WS_P8H (T0 + 24640)
#define WS_P8L (T0 + 26688)
#define WS_E   (T0 + 28736)                 /* NBATCH*NGRP*64 = 2097152 floats */
#define WS_SG  (WS_E + NBATCH * NGRP * 64)  /* same size */

typedef short bf16x8 __attribute__((ext_vector_type(8)));
typedef float f32x4  __attribute__((ext_vector_type(4)));

__device__ __forceinline__ float rl(float v, int l) {
  return __builtin_bit_cast(float,
      __builtin_amdgcn_readlane(__builtin_bit_cast(int, v), l));
}

__device__ __forceinline__ unsigned short bf16rne(float x) {
  unsigned b = __builtin_bit_cast(unsigned, x);
  return (unsigned short)((b + 0x7fffu + ((b >> 16) & 1u)) >> 16);
}
__device__ __forceinline__ void split2(float x, unsigned short& h, unsigned short& l) {
  h = bf16rne(x);
  float hf = __builtin_bit_cast(float, ((unsigned)h) << 16);
  l = bf16rne(x - hf);
}

// ---------------- pre: readlane-based 64x64 matmul, 1024 thr = 16 waves --------
__device__ __forceinline__ void mm_rl(
    float* __restrict__ dst, const float* __restrict__ Abuf,
    const float* __restrict__ Bbuf, const float* __restrict__ S1,
    const float* __restrict__ S2, int addI,
    int aShift, int bShift, int rLo, int rHi, int cLo, int cHi, int doSync) {
  if (doSync) __syncthreads();   // prior step's stores visible; prior reads done
  const int lane = threadIdx.x & 63;
  const int rb   = (threadIdx.x >> 6) << 2;        // 4 rows per wave
  if (rb >= rHi || rb + 4 <= rLo) return;          // whole wave out of range
  int bi = lane - bShift;
  bi = bi < 0 ? 0 : (bi > 63 ? 63 : bi);

  float a[4];
#pragma unroll
  for (int j = 0; j < 4; ++j) {
    int r = rb + j - aShift;
    r = r < 0 ? 0 : (r > 63 ? 63 : r);
    a[j] = Abuf[r * 64 + lane];     // lane m of this wave holds A[r][m]
  }
  float o[4] = {0.f, 0.f, 0.f, 0.f};

#pragma unroll 16
  for (int m = 0; m < 64; ++m) {
    float bv = Bbuf[m * 64 + bi];
#pragma unroll
    for (int j = 0; j < 4; ++j)
      o[j] += rl(a[j], m) * bv;     // readlane: uniform SGPR lane index
  }

#pragma unroll
  for (int j = 0; j < 4; ++j) {
    const int i = rb + j;
    float v = o[j];
    if (addI && i == lane) v += 1.f;
    if (S1) v += S1[i * 64 + lane];
    if (S2) v += S2[i * 64 + lane];
    if (i >= rLo && i < rHi && lane >= cLo && lane < cHi)
      dst[i * 64 + lane] = v;
  }
}

// Precompute (single workgroup, 1024 threads):
// X=hA; BL=(I+X4)(I+X2)(I+X) ~= (I-X)^-1; Ab=BL(I+X); Bb=step*BL@B;
// block-doubled A1 rows / gB cols; P=Ab^64; P8=P^8; K; W bf16 hi/lo;
// packed bf16 hi/lo tables for P, A1, P8 (scan fragment loads).
__global__ void __launch_bounds__(1024)
ssm_pre(const float* __restrict__ Ag, const float* __restrict__ Bg,
        const float* __restrict__ Cg, const float* __restrict__ Dg,
        const float* __restrict__ lsg, float* __restrict__ ws) {
  __shared__ float LDS[7 * 4096 + 64];
  float* L0  = LDS;
  float* L1  = LDS + 4096;
  float* L2  = LDS + 2 * 4096;
  float* L3  = LDS + 3 * 4096;
  float* L4  = LDS + 4 * 4096;
  float* gBl = LDS + 5 * 4096;   // gB[m][j] = (Ab^j Bb)[m], row-major
  float* A1l = LDS + 6 * 4096;   // A1 row i = C*Ab^(i+1)
  float* Kl  = LDS + 7 * 4096;

  const int t = threadIdx.x;
  const float step = expf(lsg[0]);
  const float h = 0.5f * step;
  const float D0 = Dg[0];

  // X = h*A
  for (int i = t; i < 4096; i += 1024) L0[i] = h * Ag[i];

  mm_rl(L1, L0, L0, nullptr, nullptr, 0, 0, 0, 0, 64, 0, 64, 1);   // X2
  mm_rl(L2, L1, L1, nullptr, nullptr, 0, 0, 0, 0, 64, 0, 64, 1);   // X4
  mm_rl(L3, L2, L1, L2, L1, 1, 0, 0, 0, 64, 0, 64, 1);             // T1=(I+X4)(I+X2)
  mm_rl(L4, L3, L0, L3, nullptr, 0, 0, 0, 0, 64, 0, 64, 1);        // BL=T1(I+X)
  mm_rl(L2, L4, L0, L4, nullptr, 0, 0, 0, 0, 64, 0, 64, 1);        // Ab=BL(I+X) -> L2
  __syncthreads();

  // Bb -> gB col 0 ; A1 row 0 = C@Ab
  if (t < 64) {
    float acc = 0.f, a1 = 0.f;
    for (int m = 0; m < 64; ++m) acc += L4[t * 64 + m] * Bg[m];
    gBl[t * 64] = step * acc;
    for (int m = 0; m < 64; ++m) a1 += Cg[m] * L2[m * 64 + t];
    A1l[t] = a1;
  }

  // Block-doubling: pw = Ab^k. Ext cols/rows [k,2k), then square.
  float* pw = L2;
  float* freebuf[4] = {L0, L1, L3, L4};
  int fi = 0;
  for (int k = 1; k <= 32; k <<= 1) {
    mm_rl(gBl, pw, gBl, nullptr, nullptr, 0, 0, k, 0, 64, k, 2 * k, 1);
    mm_rl(A1l, A1l, pw, nullptr, nullptr, 0, k, 0, k, 2 * k, 0, 64, 0);
    if (k < 32) {
      float* d = freebuf[fi]; fi = (fi + 1) & 3;
      mm_rl(d, pw, pw, nullptr, nullptr, 0, 0, 0, 0, 64, 0, 64, 0);
      pw = d;
    }
  }
  // P = Ab^64 -> L2 (Ab long dead); then P2 -> L1, P4 -> L3, P8 -> L4
  mm_rl(L2, pw, pw, nullptr, nullptr, 0, 0, 0, 0, 64, 0, 64, 1);
  mm_rl(L1, L2, L2, nullptr, nullptr, 0, 0, 0, 0, 64, 0, 64, 1);   // P^2
  mm_rl(L3, L1, L1, nullptr, nullptr, 0, 0, 0, 0, 64, 0, 64, 1);   // P^4
  mm_rl(L4, L3, L3, nullptr, nullptr, 0, 0, 0, 0, 64, 0, 64, 1);   // P^8
  __syncthreads();

  // K[r] = C . gB col r
  if (t < 64) {
    float acc = 0.f;
    for (int m = 0; m < 64; ++m) acc += Cg[m] * gBl[m * 64 + t];
    Kl[t] = acc;
  }
  __syncthreads();

  // Outputs
  float* wsP  = ws + WS_P;
  float* wsA1 = ws + WS_A1;
  unsigned short* ph  = (unsigned short*)(ws + WS_PH);
  unsigned short* pl  = (unsigned short*)(ws + WS_PL);
  unsigned short* a1h = (unsigned short*)(ws + WS_A1H);
  unsigned short* a1l = (unsigned short*)(ws + WS_A1L);
  unsigned short* p8h = (unsigned short*)(ws + WS_P8H);
  unsigned short* p8l = (unsigned short*)(ws + WS_P8L);
  for (int e = t; e < 4096; e += 1024) {
    wsP[e]  = L2[e];
    wsA1[e] = A1l[e];
    unsigned short hh, ll;
    split2(L2[e], hh, ll);  ph[e]  = hh; pl[e]  = ll;
    split2(A1l[e], hh, ll); a1h[e] = hh; a1l[e] = ll;
    split2(L4[e], hh, ll);  p8h[e] = hh; p8l[e] = ll;
  }
  unsigned short* wh = (unsigned short*)(ws + WS_WH);
  unsigned short* wl = (unsigned short*)(ws + WS_WL);
  for (int e = t; e < 8192; e += 1024) {
    int i = e >> 6, j = e & 63;
    float w;
    if (i < 64) w = ((i >= j) ? Kl[i - j] : 0.f) + ((i == j) ? D0 : 0.f);
    else        w = gBl[(i - 64) * 64 + (63 - j)];   // Brev[n][j]=(Ab^(63-j)Bb)[n]
    unsigned short hh, ll;
    split2(w, hh, ll);
    wh[e] = hh;
    wl[e] = ll;
  }
}

// Phase 1: [y0; v] = W @ U via MFMA bf16x2 (hi*hi + hi*lo + lo*hi, fp32 acc).
__global__ void __launch_bounds__(256, 2)
ssm_conv_mfma(const float* __restrict__ u, const float* __restrict__ ws,
              float* __restrict__ y, float* __restrict__ v) {
  const int lane = threadIdx.x & 63;
  const int n = lane & 15, quad = lane >> 4;
  const int wid = blockIdx.x * 4 + (threadIdx.x >> 6);

  const unsigned short* wh = (const unsigned short*)(ws + WS_WH);
  const unsigned short* wl = (const unsigned short*)(ws + WS_WL);

  bf16x8 ah[8][2], al[8][2];
#pragma unroll
  for (int t = 0; t < 8; ++t)
#pragma unroll
    for (int ks = 0; ks < 2; ++ks) {
      int off = (t * 16 + n) * 64 + ks * 32 + quad * 8;
      ah[t][ks] = *(const bf16x8*)(wh + off);
      al[t][ks] = *(const bf16x8*)(wl + off);
    }

#pragma unroll
  for (int g = 0; g < 4; ++g) {
    const int G = wid * 4 + g;
    const int row = G >> 3;
    const int c = ((G & 7) << 4) + n;
    const float* ub = u + (size_t)row * LSEQ + c * 64 + quad * 8;
    f32x4 f0 = *(const f32x4*)(ub);
    f32x4 f1 = *(const f32x4*)(ub + 4);
    f32x4 f2 = *(const f32x4*)(ub + 32);
    f32x4 f3 = *(const f32x4*)(ub + 36);

    bf16x8 bh0, bl0, bh1, bl1;
    {
      float xs0[8] = {f0[0], f0[1], f0[2], f0[3], f1[0], f1[1], f1[2], f1[3]};
      float xs1[8] = {f2[0], f2[1], f2[2], f2[3], f3[0], f3[1], f3[2], f3[3]};
#pragma unroll
      for (int j = 0; j < 8; ++j) {
        unsigned short hh, ll;
        split2(xs0[j], hh, ll);
        bh0[j] = (short)hh; bl0[j] = (short)ll;
        split2(xs1[j], hh, ll);
        bh1[j] = (short)hh; bl1[j] = (short)ll;
      }
    }

    float* ybase = y + (size_t)row * LSEQ + c * 64;
    float* vbase = v + ((size_t)row * NCHUNK + c) * 64;
#pragma unroll
    for (int t = 0; t < 8; ++t) {
      f32x4 acc = {0.f, 0.f, 0.f, 0.f};
      acc = __builtin_amdgcn_mfma_f32_16x16x32_bf16(ah[t][0], bh0, acc, 0, 0, 0);
      acc = __builtin_amdgcn_mfma_f32_16x16x32_bf16(ah[t][1], bh1, acc, 0, 0, 0);
      acc = __builtin_amdgcn_mfma_f32_16x16x32_bf16(ah[t][0], bl0, acc, 0, 0, 0);
      acc = __builtin_amdgcn_mfma_f32_16x16x32_bf16(ah[t][1], bl1, acc, 0, 0, 0);
      acc = __builtin_amdgcn_mfma_f32_16x16x32_bf16(al[t][0], bh0, acc, 0, 0, 0);
      acc = __builtin_amdgcn_mfma_f32_16x16x32_bf16(al[t][1], bh1, acc, 0, 0, 0);
      const int i0 = t * 16 + quad * 4;
      if (t < 4) *(f32x4*)(ybase + i0) = acc;
      else       *(f32x4*)(vbase + (i0 - 64)) = acc;
    }
  }
}

// -------- scan phase, sequence-split into NGRP superchunks of GLEN chunks ----
// Fragment mappings identical to ssm_conv_mfma:
//  A: lane(n,q) holds M[mt*16+n][ks*32+q*8+j]; B: S[ks*32+q*8+j][n];
//  D: [mt*16+q*4+j][n].

// E-kernel: local scan (accS only) from s=0 over GLEN chunks -> E_g.
// 512 blocks x 4 waves; wave wid -> rowgroup R=(wid>>4)*16, group g=wid&15.
__global__ void __launch_bounds__(256, 2)
ssm_scan_e(float* __restrict__ ws, const float* __restrict__ v) {
  __shared__ float SL[4][16 * 68];
  const int lane = threadIdx.x & 63;
  const int n = lane & 15, q = lane >> 4;
  const int wid = blockIdx.x * 4 + (threadIdx.x >> 6);
  const int R = (wid >> 4) * 16;
  const int g = wid & 15;
  float* sl = SL[threadIdx.x >> 6];

  const unsigned short* ph = (const unsigned short*)(ws + WS_PH);
  const unsigned short* pl = (const unsigned short*)(ws + WS_PL);
  bf16x8 Ph[4][2], Pl[4][2];
#pragma unroll
  for (int mt = 0; mt < 4; ++mt)
#pragma unroll
    for (int ks = 0; ks < 2; ++ks) {
      int off = (mt * 16 + n) * 64 + ks * 32 + q * 8;
      Ph[mt][ks] = *(const bf16x8*)(ph + off);
      Pl[mt][ks] = *(const bf16x8*)(pl + off);
    }

  bf16x8 Sbh[2], Sbl[2];
#pragma unroll
  for (int ks = 0; ks < 2; ++ks)
#pragma unroll
    for (int j = 0; j < 8; ++j) { Sbh[ks][j] = 0; Sbl[ks][j] = 0; }

  const int cb = g * GLEN;
  const float* vrow = v + ((size_t)(R + n) * NCHUNK) * 64 + q * 4;

  f32x4 vc[4];
#pragma unroll
  for (int mt = 0; mt < 4; ++mt)
    vc[mt] = *(const f32x4*)(vrow + (size_t)cb * 64 + mt * 16);

  for (int c8 = 0; c8 < GLEN; ++c8) {
    const int cn = cb + ((c8 + 1 < GLEN) ? (c8 + 1) : c8);
    f32x4 vn[4];
#pragma unroll
    for (int mt = 0; mt < 4; ++mt)
      vn[mt] = *(const f32x4*)(vrow + (size_t)cn * 64 + mt * 16);

    f32x4 accS[4];
#pragma unroll
    for (int mt = 0; mt < 4; ++mt) {
      f32x4 as = vc[mt];
      as = __builtin_amdgcn_mfma_f32_16x16x32_bf16(Ph[mt][0], Sbh[0], as, 0, 0, 0);
      as = __builtin_amdgcn_mfma_f32_16x16x32_bf16(Ph[mt][1], Sbh[1], as, 0, 0, 0);
      as = __builtin_amdgcn_mfma_f32_16x16x32_bf16(Ph[mt][0], Sbl[0], as, 0, 0, 0);
      as = __builtin_amdgcn_mfma_f32_16x16x32_bf16(Ph[mt][1], Sbl[1], as, 0, 0, 0);
      as = __builtin_amdgcn_mfma_f32_16x16x32_bf16(Pl[mt][0], Sbh[0], as, 0, 0, 0);
      as = __builtin_amdgcn_mfma_f32_16x16x32_bf16(Pl[mt][1], Sbh[1], as, 0, 0, 0);
      accS[mt] = as;
    }

    if (c8 + 1 < GLEN) {
      __syncthreads();
#pragma unroll
      for (int mt = 0; mt < 4; ++mt)
        *(f32x4*)(&sl[n * 68 + mt * 16 + q * 4]) = accS[mt];
      __syncthreads();
#pragma unroll
      for (int ks = 0; ks < 2; ++ks) {
        f32x4 s0 = *(const f32x4*)(&sl[n * 68 + ks * 32 + q * 8]);
        f32x4 s1 = *(const f32x4*)(&sl[n * 68 + ks * 32 + q * 8 + 4]);
#pragma unroll
        for (int j = 0; j < 4; ++j) {
          unsigned short hh, ll;
          split2(s0[j], hh, ll);
          Sbh[ks][j] = (short)hh; Sbl[ks][j] = (short)ll;
          split2(s1[j], hh, ll);
          Sbh[ks][j + 4] = (short)hh; Sbl[ks][j + 4] = (short)ll;
        }
      }
    } else {
      // accS == E_g : store in D-layout, [row][g][state]
      float* eb = ws + WS_E + ((size_t)(R + n) * NGRP + g) * 64 + q * 4;
#pragma unroll
      for (int mt = 0; mt < 4; ++mt)
        *(f32x4*)(eb + mt * 16) = accS[mt];
    }

    vc[0] = vn[0]; vc[1] = vn[1]; vc[2] = vn[2]; vc[3] = vn[3];
  }
}

// sigma-kernel: per row-group boundary scan sg_{g+1} = P8@sg_g + E_g,
// storing sg_g for g=0..15 (slot0 = zeros). 32 blocks x 4 waves.
__global__ void __launch_bounds__(256, 2)
ssm_scan_sg(float* __restrict__ ws) {
  __shared__ float SL[4][16 * 68];
  const int lane = threadIdx.x & 63;
  const int n = lane & 15, q = lane >> 4;
  const int wid = blockIdx.x * 4 + (threadIdx.x >> 6);
  const int R = wid * 16;
  float* sl = SL[threadIdx.x >> 6];

  const unsigned short* p8h = (const unsigned short*)(ws + WS_P8H);
  const unsigned short* p8l = (const unsigned short*)(ws + WS_P8L);
  bf16x8 Ph[4][2], Pl[4][2];
#pragma unroll
  for (int mt = 0; mt < 4; ++mt)
#pragma unroll
    for (int ks = 0; ks < 2; ++ks) {
      int off = (mt * 16 + n) * 64 + ks * 32 + q * 8;
      Ph[mt][ks] = *(const bf16x8*)(p8h + off);
      Pl[mt][ks] = *(const bf16x8*)(p8l + off);
    }

  bf16x8 Sbh[2], Sbl[2];
#pragma unroll
  for (int ks = 0; ks < 2; ++ks)
#pragma unroll
    for (int j = 0; j < 8; ++j) { Sbh[ks][j] = 0; Sbl[ks][j] = 0; }

  const float* erow = ws + WS_E + ((size_t)(R + n) * NGRP) * 64 + q * 4;
  float*       srow = ws + WS_SG + ((size_t)(R + n) * NGRP) * 64 + q * 4;

  // sg_0 = 0
  {
    f32x4 z = {0.f, 0.f, 0.f, 0.f};
#pragma unroll
    for (int mt = 0; mt < 4; ++mt) *(f32x4*)(srow + mt * 16) = z;
  }

  f32x4 ec[4];
#pragma unroll
  for (int mt = 0; mt < 4; ++mt) ec[mt] = *(const f32x4*)(erow + mt * 16);

  for (int g = 0; g < NGRP - 1; ++g) {     // need sg_1..sg_15 (E_15 unused)
    const int gn = (g + 1 < NGRP - 1) ? (g + 1) : g;
    f32x4 en[4];
#pragma unroll
    for (int mt = 0; mt < 4; ++mt)
      en[mt] = *(const f32x4*)(erow + (size_t)gn * 64 + mt * 16);

    f32x4 accS[4];
#pragma unroll
    for (int mt = 0; mt < 4; ++mt) {
      f32x4 as = ec[mt];
      as = __builtin_amdgcn_mfma_f32_16x16x32_bf16(Ph[mt][0], Sbh[0], as, 0, 0, 0);
      as = __builtin_amdgcn_mfma_f32_16x16x32_bf16(Ph[mt][1], Sbh[1], as, 0, 0, 0);
      as = __builtin_amdgcn_mfma_f32_16x16x32_bf16(Ph[mt][0], Sbl[0], as, 0, 0, 0);
      as = __builtin_amdgcn_mfma_f32_16x16x32_bf16(Ph[mt][1], Sbl[1], as, 0, 0, 0);
      as = __builtin_amdgcn_mfma_f32_16x16x32_bf16(Pl[mt][0], Sbh[0], as, 0, 0, 0);
      as = __builtin_amdgcn_mfma_f32_16x16x32_bf16(Pl[mt][1], Sbh[1], as, 0, 0, 0);
      accS[mt] = as;
    }

    // store sg_{g+1}
#pragma unroll
    for (int mt = 0; mt < 4; ++mt)
      *(f32x4*)(srow + (size_t)(g + 1) * 64 + mt * 16) = accS[mt];

    if (g + 1 < NGRP - 1) {
      __syncthreads();
#pragma unroll
      for (int mt = 0; mt < 4; ++mt)
        *(f32x4*)(&sl[n * 68 + mt * 16 + q * 4]) = accS[mt];
      __syncthreads();
#pragma unroll
      for (int ks = 0; ks < 2; ++ks) {
        f32x4 s0 = *(const f32x4*)(&sl[n * 68 + ks * 32 + q * 8]);
        f32x4 s1 = *(const f32x4*)(&sl[n * 68 + ks * 32 + q * 8 + 4]);
#pragma unroll
        for (int j = 0; j < 4; ++j) {
          unsigned short hh, ll;
          split2(s0[j], hh, ll);
          Sbh[ks][j] = (short)hh; Sbl[ks][j] = (short)ll;
          split2(s1[j], hh, ll);
          Sbh[ks][j + 4] = (short)hh; Sbl[ks][j + 4] = (short)ll;
        }
      }
    }

    ec[0] = en[0]; ec[1] = en[1]; ec[2] = en[2]; ec[3] = en[3];
  }
}

// Main scan: per (rowgroup,superchunk) wave, start from sg_g, GLEN chunks.
// 512 blocks x 4 waves.
__global__ void __launch_bounds__(256, 2)
ssm_scan_mfma(const float* __restrict__ ws, const float* __restrict__ v,
              float* __restrict__ y) {
  __shared__ float SL[4][16 * 68];
  const int lane = threadIdx.x & 63;
  const int n = lane & 15, q = lane >> 4;
  const int wid = blockIdx.x * 4 + (threadIdx.x >> 6);
  const int R = (wid >> 4) * 16;
  const int g = wid & 15;
  float* sl = SL[threadIdx.x >> 6];

  const unsigned short* ph  = (const unsigned short*)(ws + WS_PH);
  const unsigned short* pll = (const unsigned short*)(ws + WS_PL);
  const unsigned short* a1h = (const unsigned short*)(ws + WS_A1H);
  const unsigned short* a1l = (const unsigned short*)(ws + WS_A1L);

  bf16x8 Ph[4][2], Pl[4][2], Ah[4][2], Al[4][2];
#pragma unroll
  for (int mt = 0; mt < 4; ++mt)
#pragma unroll
    for (int ks = 0; ks < 2; ++ks) {
      int off = (mt * 16 + n) * 64 + ks * 32 + q * 8;
      Ph[mt][ks] = *(const bf16x8*)(ph + off);
      Pl[mt][ks] = *(const bf16x8*)(pll + off);
      Ah[mt][ks] = *(const bf16x8*)(a1h + off);
      Al[mt][ks] = *(const bf16x8*)(a1l + off);
    }

  // S init from sg_g (B-fragment layout: lane(n,q) needs sg[row R+n][k])
  bf16x8 Sbh[2], Sbl[2];
  {
    const float* sgp = ws + WS_SG + ((size_t)(R + n) * NGRP + g) * 64;
#pragma unroll
    for (int ks = 0; ks < 2; ++ks) {
      f32x4 s0 = *(const f32x4*)(sgp + ks * 32 + q * 8);
      f32x4 s1 = *(const f32x4*)(sgp + ks * 32 + q * 8 + 4);
#pragma unroll
      for (int j = 0; j < 4; ++j) {
        unsigned short hh, ll;
        split2(s0[j], hh, ll);
        Sbh[ks][j] = (short)hh; Sbl[ks][j] = (short)ll;
        split2(s1[j], hh, ll);
        Sbh[ks][j + 4] = (short)hh; Sbl[ks][j + 4] = (short)ll;
      }
    }
  }

  const int cb = g * GLEN;
  const float* vrow = v + ((size_t)(R + n) * NCHUNK) * 64 + q * 4;
  float*       yrow = y + (size_t)(R + n) * LSEQ + q * 4;

  f32x4 vc[4], yc[4];
#pragma unroll
  for (int mt = 0; mt < 4; ++mt) {
    vc[mt] = *(const f32x4*)(vrow + (size_t)cb * 64 + mt * 16);
    yc[mt] = *(const f32x4*)(yrow + (size_t)cb * 64 + mt * 16);
  }

  for (int c8 = 0; c8 < GLEN; ++c8) {
    const int c = cb + c8;
    const int cn = cb + ((c8 + 1 < GLEN) ? (c8 + 1) : c8);
    f32x4 vn[4], yn[4];
#pragma unroll
    for (int mt = 0; mt < 4; ++mt) {
      vn[mt] = *(const f32x4*)(vrow + (size_t)cn * 64 + mt * 16);
      yn[mt] = *(const f32x4*)(yrow + (size_t)cn * 64 + mt * 16);
    }

    f32x4 accS[4], accY[4];
#pragma unroll
    for (int mt = 0; mt < 4; ++mt) {
      f32x4 as = vc[mt];
      as = __builtin_amdgcn_mfma_f32_16x16x32_bf16(Ph[mt][0], Sbh[0], as, 0, 0, 0);
      as = __builtin_amdgcn_mfma_f32_16x16x32_bf16(Ph[mt][1], Sbh[1], as, 0, 0, 0);
      as = __builtin_amdgcn_mfma_f32_16x16x32_bf16(Ph[mt][0], Sbl[0], as, 0, 0, 0);
      as = __builtin_amdgcn_mfma_f32_16x16x32_bf16(Ph[mt][1], Sbl[1], as, 0, 0, 0);
      as = __builtin_amdgcn_mfma_f32_16x16x32_bf16(Pl[mt][0], Sbh[0], as, 0, 0, 0);
      as = __builtin_amdgcn_mfma_f32_16x16x32_bf16(Pl[mt][1], Sbh[1], as, 0, 0, 0);
      accS[mt] = as;
      f32x4 ay = yc[mt];
      ay = __builtin_amdgcn_mfma_f32_16x16x32_bf16(Ah[mt][0], Sbh[0], ay, 0, 0, 0);
      ay = __builtin_amdgcn_mfma_f32_16x16x32_bf16(Ah[mt][1], Sbh[1], ay, 0, 0, 0);
      ay = __builtin_amdgcn_mfma_f32_16x16x32_bf16(Ah[mt][0], Sbl[0], ay, 0, 0, 0);
      ay = __builtin_amdgcn_mfma_f32_16x16x32_bf16(Ah[mt][1], Sbl[1], ay, 0, 0, 0);
      ay = __builtin_amdgcn_mfma_f32_16x16x32_bf16(Al[mt][0], Sbh[0], ay, 0, 0, 0);
      ay = __builtin_amdgcn_mfma_f32_16x16x32_bf16(Al[mt][1], Sbh[1], ay, 0, 0, 0);
      accY[mt] = ay;
    }

#pragma unroll
    for (int mt = 0; mt < 4; ++mt)
      *(f32x4*)(yrow + (size_t)c * 64 + mt * 16) = accY[mt];

    if (c8 + 1 < GLEN) {
      __syncthreads();
#pragma unroll
      for (int mt = 0; mt < 4; ++mt)
        *(f32x4*)(&sl[n * 68 + mt * 16 + q * 4]) = accS[mt];
      __syncthreads();
#pragma unroll
      for (int ks = 0; ks < 2; ++ks) {
        f32x4 s0 = *(const f32x4*)(&sl[n * 68 + ks * 32 + q * 8]);
        f32x4 s1 = *(const f32x4*)(&sl[n * 68 + ks * 32 + q * 8 + 4]);
#pragma unroll
        for (int j = 0; j < 4; ++j) {
          unsigned short hh, ll;
          split2(s0[j], hh, ll);
          Sbh[ks][j] = (short)hh; Sbl[ks][j] = (short)ll;
          split2(s1[j], hh, ll);
          Sbh[ks][j + 4] = (short)hh; Sbl[ks][j + 4] = (short)ll;
        }
      }
    }

    vc[0] = vn[0]; vc[1] = vn[1]; vc[2] = vn[2]; vc[3] = vn[3];
    yc[0] = yn[0]; yc[1] = yn[1]; yc[2] = yn[2]; yc[3] = yn[3];
  }
}

extern "C" void kernel_launch(void* const* d_in, const int* in_sizes, int n_in,
                              void* d_out, int out_size, void* d_ws, size_t ws_size,
                              hipStream_t stream) {
  const float* u  = (const float*)d_in[0];
  const float* A  = (const float*)d_in[1];
  const float* B  = (const float*)d_in[2];
  const float* C  = (const float*)d_in[3];
  const float* D  = (const float*)d_in[4];
  const float* ls = (const float*)d_in[5];
  float* ws  = (float*)d_ws;
  float* out = (float*)d_out;
  float* v   = ws + WS_V;

  ssm_pre<<<dim3(1), dim3(1024), 0, stream>>>(A, B, C, D, ls, ws);
  ssm_conv_mfma<<<dim3(1024), dim3(256), 0, stream>>>(u, ws, out, v);
  ssm_scan_e<<<dim3(512), dim3(256), 0, stream>>>(ws, v);
  ssm_scan_sg<<<dim3(32), dim3(256), 0, stream>>>(ws);
  ssm_scan_mfma<<<dim3(512), dim3(256), 0, stream>>>(ws, v, out);
}

// Round 4
// 262.737 us; speedup vs baseline: 1.3855x; 1.2831x over previous
//
#include <hip/hip_runtime.h>
#include <math.h>

#define LSEQ   8192
#define CHUNK  64
#define NCHUNK 128
#define NBATCH 2048
#define NGRP   16      /* superchunks */
#define GLEN   8       /* chunks per superchunk: NGRP*GLEN == NCHUNK */

// ws float layout:
//   [0]        v (NBATCH*NCHUNK*64 = 16777216 floats)
//   [T0]       tables, then E (2M floats), then SG (2M floats)
#define WS_V   0
#define T0     (NBATCH * NCHUNK * 64)
#define WS_P   (T0)
#define WS_A1  (T0 + 4096)
#define WS_K   (T0 + 8192)
#define WS_WH  (T0 + 8256)    /* 4096 floats = 8192 bf16: W hi, row-major 128x64 */
#define WS_WL  (T0 + 12352)   /* 4096 floats: W lo */
#define WS_PH  (T0 + 16448)   /* 2048 floats = 4096 bf16: P hi, row-major 64x64 */
#define WS_PL  (T0 + 18496)
#define WS_A1H (T0 + 20544)
#define WS_A1L (T0 + 22592)
#define WS_P8H (T0 + 24640)
#define WS_P8L (T0 + 26688)
#define WS_E   (T0 + 28736)                 /* NBATCH*NGRP*64 = 2097152 floats */
#define WS_SG  (WS_E + NBATCH * NGRP * 64)  /* same size */

typedef short bf16x8 __attribute__((ext_vector_type(8)));
typedef float f32x4  __attribute__((ext_vector_type(4)));
typedef unsigned short u16;

__device__ __forceinline__ u16 bf16rne(float x) {
  unsigned b = __builtin_bit_cast(unsigned, x);
  return (u16)((b + 0x7fffu + ((b >> 16) & 1u)) >> 16);
}
__device__ __forceinline__ float bf2f(u16 h) {
  return __builtin_bit_cast(float, ((unsigned)h) << 16);
}
__device__ __forceinline__ void split2(float x, u16& h, u16& l) {
  h = bf16rne(x);
  l = bf16rne(x - bf2f(h));
}
__device__ __forceinline__ void split3(float x, u16& h, u16& m, u16& l) {
  h = bf16rne(x);
  float r = x - bf2f(h);
  m = bf16rne(r);
  r -= bf2f(m);
  l = bf16rne(r);
}

// ---------------- pre: MFMA triple-bf16 64x64 matmuls --------------------
// Matrices stored in LDS as bf16 triples (h at +0, m at +4096, l at +8192,
// u16 units), row-major with XOR swizzle on the 8-col group to avoid the
// 16-way bank conflict of stride-128B ds_read_b128 (G4/T2).
__device__ __forceinline__ int swz(int r, int c) {
  return r * 64 + (c ^ ((r & 7) << 3));
}
__device__ __forceinline__ float tri_get(const u16* p, int r, int c) {
  const int e = swz(r, c);
  return bf2f(p[e]) + bf2f(p[4096 + e]) + bf2f(p[8192 + e]);
}

// One 16x16 output tile of OUT = Ashift . B  (+ add1 + add2 + addI*I),
// where the B OPERAND's columns are read as rows of B3 (B3 holds B^T
// row-major — the pair trick makes every fragment load contiguous).
// A-frag rows shifted by aShift (row r of OUT uses A row r-aShift, clamped;
// garbage only reaches rows masked out by [rLo,rHi)).
// Fragment mappings identical to ssm_conv_mfma (verified):
//  A: lane(n,q) holds M[mt*16+n][ks*32+q*8+j]; B: B[ks*32+q*8+j][nt*16+n];
//  D: lane(n,q) elem j -> row mt*16+q*4+j, col nt*16+n.
__device__ __forceinline__ void mfma_tile3(
    const u16* __restrict__ A3, const u16* __restrict__ B3, u16* __restrict__ D3,
    int mt, int nt, int aShift,
    const u16* add1, const u16* add2, int addI, int rLo, int rHi) {
  const int lane = threadIdx.x & 63;
  const int n = lane & 15, q = lane >> 4;
  int ar = mt * 16 + n - aShift;
  ar = ar < 0 ? 0 : (ar > 63 ? 63 : ar);
  const int bc = nt * 16 + n;
  bf16x8 ah[2], am[2], al[2], bh[2], bm[2], bl[2];
#pragma unroll
  for (int ks = 0; ks < 2; ++ks) {
    const int ao = swz(ar, ks * 32 + q * 8);
    const int bo = swz(bc, ks * 32 + q * 8);
    ah[ks] = *(const bf16x8*)(A3 + ao);
    am[ks] = *(const bf16x8*)(A3 + 4096 + ao);
    al[ks] = *(const bf16x8*)(A3 + 8192 + ao);
    bh[ks] = *(const bf16x8*)(B3 + bo);
    bm[ks] = *(const bf16x8*)(B3 + 4096 + bo);
    bl[ks] = *(const bf16x8*)(B3 + 8192 + bo);
  }
  f32x4 acc = {0.f, 0.f, 0.f, 0.f};
#define MF(a, b) acc = __builtin_amdgcn_mfma_f32_16x16x32_bf16(a, b, acc, 0, 0, 0)
  MF(ah[0], bh[0]); MF(ah[1], bh[1]);
  MF(ah[0], bm[0]); MF(ah[1], bm[1]);
  MF(am[0], bh[0]); MF(am[1], bh[1]);
  MF(ah[0], bl[0]); MF(ah[1], bl[1]);
  MF(am[0], bm[0]); MF(am[1], bm[1]);
  MF(al[0], bh[0]); MF(al[1], bh[1]);
#undef MF
#pragma unroll
  for (int j = 0; j < 4; ++j) {
    const int i = mt * 16 + q * 4 + j, c = nt * 16 + n;
    float v = acc[j];
    if (add1) v += tri_get(add1, i, c);
    if (add2) v += tri_get(add2, i, c);
    if (addI && i == c) v += 1.f;
    if (i >= rLo && i < rHi) {
      u16 h3, m3, l3; split3(v, h3, m3, l3);
      const int e = swz(i, c);
      D3[e] = h3; D3[4096 + e] = m3; D3[8192 + e] = l3;
    }
  }
}

// Full 64x64 product pair: OUT_F = P.Q (+addF), OUT_T = (P.Q)^T = Q^T.P^T
// (+addT). Pf holds P row-major; Qt holds Q^T row-major. Forward tiles read
// A from Pf, B-cols of Q = rows of Qt; transpose tiles read A from Qt,
// B-cols of P^T = rows of Pf. 32 tiles over 16 waves.
__device__ __forceinline__ void pair_phase(
    const u16* Pf, const u16* Qt, u16* Fn, u16* Tn,
    const u16* addF1, const u16* addT1, int addI) {
  __syncthreads();
  const int w = threadIdx.x >> 6;
#pragma unroll
  for (int tix = w; tix < 32; tix += 16) {
    if (tix < 16) mfma_tile3(Pf, Qt, Fn, tix >> 2, tix & 3, 0, addF1, 0, addI, 0, 64);
    else { const int s = tix - 16; mfma_tile3(Qt, Pf, Tn, s >> 2, s & 3, 0, addT1, 0, addI, 0, 64); }
  }
}
// Single 64x64 product (16 tiles, one per wave), two additive terms + I.
__device__ __forceinline__ void single_phase(
    const u16* A3, const u16* B3, u16* D3,
    const u16* add1, const u16* add2, int addI) {
  __syncthreads();
  const int w = threadIdx.x >> 6;
  mfma_tile3(A3, B3, D3, w >> 2, w & 3, 0, add1, add2, addI, 0, 64);
}

// Precompute (single workgroup, 1024 threads = 16 waves), all matmuls on the
// matrix pipe with fp32-class precision (triple-bf16, 6 products):
// X=hA; BL=(I+X4)(I+X2)(I+X) ~= (I-X)^-1; Ab=BL(I+X); Bb=step*BL@B;
// block-doubled gBT rows / A1 rows (transpose-pair trick); P=Ab^64; P8;
// K; W bf16 hi/lo; ph/pl, a1h/a1l, p8h/p8l scan tables.
__global__ void __launch_bounds__(1024)
ssm_pre(const float* __restrict__ Ag, const float* __restrict__ Bg,
        const float* __restrict__ Cg, const float* __restrict__ Dg,
        const float* __restrict__ lsg, float* __restrict__ ws) {
  __shared__ __attribute__((aligned(16))) u16 TRI[6][3 * 4096];
  __shared__ float Kl[64];
  u16* tri0 = TRI[0]; u16* tri1 = TRI[1]; u16* tri2 = TRI[2];
  u16* tri3 = TRI[3]; u16* tri4 = TRI[4]; u16* tri5 = TRI[5];

  const int t = threadIdx.x;
  const int w = t >> 6;
  const float step = expf(lsg[0]);
  const float hstep = 0.5f * step;
  const float D0 = Dg[0];

  // phase 0a: X = h*A -> tri0 (split3); fp32 copy in tri2 region (temp)
  float* Xf = (float*)tri2;
  for (int e = t; e < 4096; e += 1024) {
    const float x = hstep * Ag[e];
    Xf[e] = x;
    u16 h3, m3, l3; split3(x, h3, m3, l3);
    const int s = swz(e >> 6, e & 63);
    tri0[s] = h3; tri0[4096 + s] = m3; tri0[8192 + s] = l3;
  }
  __syncthreads();
  // phase 0b: XT -> tri1
  for (int e = t; e < 4096; e += 1024) {
    const int r = e >> 6, c = e & 63;
    const float x = Xf[c * 64 + r];
    u16 h3, m3, l3; split3(x, h3, m3, l3);
    const int s = swz(r, c);
    tri1[s] = h3; tri1[4096 + s] = m3; tri1[8192 + s] = l3;
  }
  // phase 1: X2 pair -> (tri2, tri3)   [Xf temp dead]
  pair_phase(tri0, tri1, tri2, tri3, 0, 0, 0);
  // phase 2: X4 pair -> (tri4, tri5)
  pair_phase(tri2, tri3, tri4, tri5, 0, 0, 0);
  // phase 3: T1 = X4.X2 + X4 + X2 + I -> tri0   [X dead]
  single_phase(tri4, tri3, tri0, tri4, tri2, 1);
  // phase 4: T1T = X2T.X4T + X2T + X4T + I -> tri2   [X2 dead]
  single_phase(tri3, tri4, tri2, tri3, tri5, 1);
  // phase 5: BL = T1.X + T1 -> tri3 ; BLT = XT.T1T + T1T -> tri5
  pair_phase(tri0, tri1, tri3, tri5, tri0, tri2, 0);
  // phase 6: Ab = BL.X + BL -> tri4 ; AbT = XT.BLT + BLT -> tri2
  pair_phase(tri3, tri1, tri4, tri2, tri3, tri5, 0);

  // phase 7: Bb -> gBT(tri0) row 0 ; A1 row 0 = C@Ab -> A1(tri1) row 0
  __syncthreads();
  if (t < 64) {
    float acc = 0.f;
    for (int m = 0; m < 64; ++m) acc += tri_get(tri3, t, m) * Bg[m];  // BL row t
    const float bb = step * acc;
    u16 h3, m3, l3; split3(bb, h3, m3, l3);
    const int s = swz(0, t);
    tri0[s] = h3; tri0[4096 + s] = m3; tri0[8192 + s] = l3;
  } else if (t < 128) {
    const int r = t - 64;
    float acc = 0.f;
    for (int m = 0; m < 64; ++m) acc += tri_get(tri2, r, m) * Cg[m];  // AbT row r
    u16 h3, m3, l3; split3(acc, h3, m3, l3);
    const int s = swz(0, r);
    tri1[s] = h3; tri1[4096 + s] = m3; tri1[8192 + s] = l3;
  }

  // Block-doubling: cur pair = (Ab^k, Ab^k ^T). Per k one phase:
  //   squares -> next pair; gBT rows [k,2k) = gBT[0:k) @ pwT (B-frags from
  //   pw=curF); A1 rows [k,2k) = A1[0:k) @ pw (B-frags from pwT=curT).
  u16 *curF = tri4, *curT = tri2, *nxtF = tri3, *nxtT = tri5;
  for (int k = 1; k <= 32; k <<= 1) {
    __syncthreads();
    const int mtLo = k >> 4, mtHi = (2 * k - 1) >> 4;
    const int cnt = (mtHi - mtLo + 1) * 4;
    const int total = 32 + 2 * cnt;
    for (int tix = w; tix < total; tix += 16) {
      if (tix < 16) {
        mfma_tile3(curF, curT, nxtF, tix >> 2, tix & 3, 0, 0, 0, 0, 0, 64);
      } else if (tix < 32) {
        const int s = tix - 16;
        mfma_tile3(curT, curF, nxtT, s >> 2, s & 3, 0, 0, 0, 0, 0, 64);
      } else if (tix < 32 + cnt) {
        const int s = tix - 32;
        mfma_tile3(tri0, curF, tri0, mtLo + (s >> 2), s & 3, k, 0, 0, 0, k, 2 * k);
      } else {
        const int s = tix - 32 - cnt;
        mfma_tile3(tri1, curT, tri1, mtLo + (s >> 2), s & 3, k, 0, 0, 0, k, 2 * k);
      }
    }
    u16* tmp;
    tmp = curF; curF = nxtF; nxtF = tmp;
    tmp = curT; curT = nxtT; nxtT = tmp;
  }

  // P tables (curF = Ab^64)
  __syncthreads();
  float* wsP  = ws + WS_P;
  float* wsA1 = ws + WS_A1;
  u16* ph  = (u16*)(ws + WS_PH);
  u16* pl  = (u16*)(ws + WS_PL);
  u16* a1h = (u16*)(ws + WS_A1H);
  u16* a1l = (u16*)(ws + WS_A1L);
  u16* p8h = (u16*)(ws + WS_P8H);
  u16* p8l = (u16*)(ws + WS_P8L);
  for (int e = t; e < 4096; e += 1024) {
    const float x = tri_get(curF, e >> 6, e & 63);
    wsP[e] = x;
    u16 hh, ll; split2(x, hh, ll); ph[e] = hh; pl[e] = ll;
  }
  // tail: P2, P4, P8 (pair squarings)
  for (int r2 = 0; r2 < 3; ++r2) {
    pair_phase(curF, curT, nxtF, nxtT, 0, 0, 0);
    u16* tmp;
    tmp = curF; curF = nxtF; nxtF = tmp;
    tmp = curT; curT = nxtT; nxtT = tmp;
  }
  __syncthreads();
  // P8 + A1 tables
  for (int e = t; e < 4096; e += 1024) {
    const int r = e >> 6, c = e & 63;
    float x = tri_get(curF, r, c);
    u16 hh, ll; split2(x, hh, ll); p8h[e] = hh; p8l[e] = ll;
    const float a1v = tri_get(tri1, r, c);
    wsA1[e] = a1v;
    split2(a1v, hh, ll); a1h[e] = hh; a1l[e] = ll;
  }
  // K[r] = C . gB col r = gBT row r . C
  if (t < 64) {
    float acc = 0.f;
    for (int m = 0; m < 64; ++m) acc += Cg[m] * tri_get(tri0, t, m);
    Kl[t] = acc;
  }
  __syncthreads();
  // W table: [Kmat + D*I ; Brev] bf16 hi/lo
  u16* wh = (u16*)(ws + WS_WH);
  u16* wl = (u16*)(ws + WS_WL);
  for (int e = t; e < 8192; e += 1024) {
    const int i = e >> 6, j = e & 63;
    float wv;
    if (i < 64) wv = ((i >= j) ? Kl[i - j] : 0.f) + ((i == j) ? D0 : 0.f);
    else        wv = tri_get(tri0, 63 - j, i - 64);   // gB[m][jj] = gBT[jj][m]
    u16 hh, ll; split2(wv, hh, ll);
    wh[e] = hh;
    wl[e] = ll;
  }
}

// Phase 1: [y0; v] = W @ U via MFMA bf16x2 (hi*hi + hi*lo + lo*hi, fp32 acc).
__global__ void __launch_bounds__(256, 2)
ssm_conv_mfma(const float* __restrict__ u, const float* __restrict__ ws,
              float* __restrict__ y, float* __restrict__ v) {
  const int lane = threadIdx.x & 63;
  const int n = lane & 15, quad = lane >> 4;
  const int wid = blockIdx.x * 4 + (threadIdx.x >> 6);

  const unsigned short* wh = (const unsigned short*)(ws + WS_WH);
  const unsigned short* wl = (const unsigned short*)(ws + WS_WL);

  bf16x8 ah[8][2], al[8][2];
#pragma unroll
  for (int t = 0; t < 8; ++t)
#pragma unroll
    for (int ks = 0; ks < 2; ++ks) {
      int off = (t * 16 + n) * 64 + ks * 32 + quad * 8;
      ah[t][ks] = *(const bf16x8*)(wh + off);
      al[t][ks] = *(const bf16x8*)(wl + off);
    }

#pragma unroll
  for (int g = 0; g < 4; ++g) {
    const int G = wid * 4 + g;
    const int row = G >> 3;
    const int c = ((G & 7) << 4) + n;
    const float* ub = u + (size_t)row * LSEQ + c * 64 + quad * 8;
    f32x4 f0 = *(const f32x4*)(ub);
    f32x4 f1 = *(const f32x4*)(ub + 4);
    f32x4 f2 = *(const f32x4*)(ub + 32);
    f32x4 f3 = *(const f32x4*)(ub + 36);

    bf16x8 bh0, bl0, bh1, bl1;
    {
      float xs0[8] = {f0[0], f0[1], f0[2], f0[3], f1[0], f1[1], f1[2], f1[3]};
      float xs1[8] = {f2[0], f2[1], f2[2], f2[3], f3[0], f3[1], f3[2], f3[3]};
#pragma unroll
      for (int j = 0; j < 8; ++j) {
        u16 hh, ll;
        split2(xs0[j], hh, ll);
        bh0[j] = (short)hh; bl0[j] = (short)ll;
        split2(xs1[j], hh, ll);
        bh1[j] = (short)hh; bl1[j] = (short)ll;
      }
    }

    float* ybase = y + (size_t)row * LSEQ + c * 64;
    float* vbase = v + ((size_t)row * NCHUNK + c) * 64;
#pragma unroll
    for (int t = 0; t < 8; ++t) {
      f32x4 acc = {0.f, 0.f, 0.f, 0.f};
      acc = __builtin_amdgcn_mfma_f32_16x16x32_bf16(ah[t][0], bh0, acc, 0, 0, 0);
      acc = __builtin_amdgcn_mfma_f32_16x16x32_bf16(ah[t][1], bh1, acc, 0, 0, 0);
      acc = __builtin_amdgcn_mfma_f32_16x16x32_bf16(ah[t][0], bl0, acc, 0, 0, 0);
      acc = __builtin_amdgcn_mfma_f32_16x16x32_bf16(ah[t][1], bl1, acc, 0, 0, 0);
      acc = __builtin_amdgcn_mfma_f32_16x16x32_bf16(al[t][0], bh0, acc, 0, 0, 0);
      acc = __builtin_amdgcn_mfma_f32_16x16x32_bf16(al[t][1], bh1, acc, 0, 0, 0);
      const int i0 = t * 16 + quad * 4;
      if (t < 4) *(f32x4*)(ybase + i0) = acc;
      else       *(f32x4*)(vbase + (i0 - 64)) = acc;
    }
  }
}

// -------- scan phase, sequence-split into NGRP superchunks of GLEN chunks ----
// E-kernel: local scan (accS only) from s=0 over GLEN chunks -> E_g.
__global__ void __launch_bounds__(256, 2)
ssm_scan_e(float* __restrict__ ws, const float* __restrict__ v) {
  __shared__ float SL[4][16 * 68];
  const int lane = threadIdx.x & 63;
  const int n = lane & 15, q = lane >> 4;
  const int wid = blockIdx.x * 4 + (threadIdx.x >> 6);
  const int R = (wid >> 4) * 16;
  const int g = wid & 15;
  float* sl = SL[threadIdx.x >> 6];

  const unsigned short* ph = (const unsigned short*)(ws + WS_PH);
  const unsigned short* pl = (const unsigned short*)(ws + WS_PL);
  bf16x8 Ph[4][2], Pl[4][2];
#pragma unroll
  for (int mt = 0; mt < 4; ++mt)
#pragma unroll
    for (int ks = 0; ks < 2; ++ks) {
      int off = (mt * 16 + n) * 64 + ks * 32 + q * 8;
      Ph[mt][ks] = *(const bf16x8*)(ph + off);
      Pl[mt][ks] = *(const bf16x8*)(pl + off);
    }

  bf16x8 Sbh[2], Sbl[2];
#pragma unroll
  for (int ks = 0; ks < 2; ++ks)
#pragma unroll
    for (int j = 0; j < 8; ++j) { Sbh[ks][j] = 0; Sbl[ks][j] = 0; }

  const int cb = g * GLEN;
  const float* vrow = v + ((size_t)(R + n) * NCHUNK) * 64 + q * 4;

  f32x4 vc[4];
#pragma unroll
  for (int mt = 0; mt < 4; ++mt)
    vc[mt] = *(const f32x4*)(vrow + (size_t)cb * 64 + mt * 16);

  for (int c8 = 0; c8 < GLEN; ++c8) {
    const int cn = cb + ((c8 + 1 < GLEN) ? (c8 + 1) : c8);
    f32x4 vn[4];
#pragma unroll
    for (int mt = 0; mt < 4; ++mt)
      vn[mt] = *(const f32x4*)(vrow + (size_t)cn * 64 + mt * 16);

    f32x4 accS[4];
#pragma unroll
    for (int mt = 0; mt < 4; ++mt) {
      f32x4 as = vc[mt];
      as = __builtin_amdgcn_mfma_f32_16x16x32_bf16(Ph[mt][0], Sbh[0], as, 0, 0, 0);
      as = __builtin_amdgcn_mfma_f32_16x16x32_bf16(Ph[mt][1], Sbh[1], as, 0, 0, 0);
      as = __builtin_amdgcn_mfma_f32_16x16x32_bf16(Ph[mt][0], Sbl[0], as, 0, 0, 0);
      as = __builtin_amdgcn_mfma_f32_16x16x32_bf16(Ph[mt][1], Sbl[1], as, 0, 0, 0);
      as = __builtin_amdgcn_mfma_f32_16x16x32_bf16(Pl[mt][0], Sbh[0], as, 0, 0, 0);
      as = __builtin_amdgcn_mfma_f32_16x16x32_bf16(Pl[mt][1], Sbh[1], as, 0, 0, 0);
      accS[mt] = as;
    }

    if (c8 + 1 < GLEN) {
      __syncthreads();
#pragma unroll
      for (int mt = 0; mt < 4; ++mt)
        *(f32x4*)(&sl[n * 68 + mt * 16 + q * 4]) = accS[mt];
      __syncthreads();
#pragma unroll
      for (int ks = 0; ks < 2; ++ks) {
        f32x4 s0 = *(const f32x4*)(&sl[n * 68 + ks * 32 + q * 8]);
        f32x4 s1 = *(const f32x4*)(&sl[n * 68 + ks * 32 + q * 8 + 4]);
#pragma unroll
        for (int j = 0; j < 4; ++j) {
          u16 hh, ll;
          split2(s0[j], hh, ll);
          Sbh[ks][j] = (short)hh; Sbl[ks][j] = (short)ll;
          split2(s1[j], hh, ll);
          Sbh[ks][j + 4] = (short)hh; Sbl[ks][j + 4] = (short)ll;
        }
      }
    } else {
      float* eb = ws + WS_E + ((size_t)(R + n) * NGRP + g) * 64 + q * 4;
#pragma unroll
      for (int mt = 0; mt < 4; ++mt)
        *(f32x4*)(eb + mt * 16) = accS[mt];
    }

    vc[0] = vn[0]; vc[1] = vn[1]; vc[2] = vn[2]; vc[3] = vn[3];
  }
}

// sigma-kernel: per row-group boundary scan sg_{g+1} = P8@sg_g + E_g.
__global__ void __launch_bounds__(256, 2)
ssm_scan_sg(float* __restrict__ ws) {
  __shared__ float SL[4][16 * 68];
  const int lane = threadIdx.x & 63;
  const int n = lane & 15, q = lane >> 4;
  const int wid = blockIdx.x * 4 + (threadIdx.x >> 6);
  const int R = wid * 16;
  float* sl = SL[threadIdx.x >> 6];

  const unsigned short* p8h = (const unsigned short*)(ws + WS_P8H);
  const unsigned short* p8l = (const unsigned short*)(ws + WS_P8L);
  bf16x8 Ph[4][2], Pl[4][2];
#pragma unroll
  for (int mt = 0; mt < 4; ++mt)
#pragma unroll
    for (int ks = 0; ks < 2; ++ks) {
      int off = (mt * 16 + n) * 64 + ks * 32 + q * 8;
      Ph[mt][ks] = *(const bf16x8*)(p8h + off);
      Pl[mt][ks] = *(const bf16x8*)(p8l + off);
    }

  bf16x8 Sbh[2], Sbl[2];
#pragma unroll
  for (int ks = 0; ks < 2; ++ks)
#pragma unroll
    for (int j = 0; j < 8; ++j) { Sbh[ks][j] = 0; Sbl[ks][j] = 0; }

  const float* erow = ws + WS_E + ((size_t)(R + n) * NGRP) * 64 + q * 4;
  float*       srow = ws + WS_SG + ((size_t)(R + n) * NGRP) * 64 + q * 4;

  {
    f32x4 z = {0.f, 0.f, 0.f, 0.f};
#pragma unroll
    for (int mt = 0; mt < 4; ++mt) *(f32x4*)(srow + mt * 16) = z;
  }

  f32x4 ec[4];
#pragma unroll
  for (int mt = 0; mt < 4; ++mt) ec[mt] = *(const f32x4*)(erow + mt * 16);

  for (int g = 0; g < NGRP - 1; ++g) {
    const int gn = (g + 1 < NGRP - 1) ? (g + 1) : g;
    f32x4 en[4];
#pragma unroll
    for (int mt = 0; mt < 4; ++mt)
      en[mt] = *(const f32x4*)(erow + (size_t)gn * 64 + mt * 16);

    f32x4 accS[4];
#pragma unroll
    for (int mt = 0; mt < 4; ++mt) {
      f32x4 as = ec[mt];
      as = __builtin_amdgcn_mfma_f32_16x16x32_bf16(Ph[mt][0], Sbh[0], as, 0, 0, 0);
      as = __builtin_amdgcn_mfma_f32_16x16x32_bf16(Ph[mt][1], Sbh[1], as, 0, 0, 0);
      as = __builtin_amdgcn_mfma_f32_16x16x32_bf16(Ph[mt][0], Sbl[0], as, 0, 0, 0);
      as = __builtin_amdgcn_mfma_f32_16x16x32_bf16(Ph[mt][1], Sbl[1], as, 0, 0, 0);
      as = __builtin_amdgcn_mfma_f32_16x16x32_bf16(Pl[mt][0], Sbh[0], as, 0, 0, 0);
      as = __builtin_amdgcn_mfma_f32_16x16x32_bf16(Pl[mt][1], Sbh[1], as, 0, 0, 0);
      accS[mt] = as;
    }

#pragma unroll
    for (int mt = 0; mt < 4; ++mt)
      *(f32x4*)(srow + (size_t)(g + 1) * 64 + mt * 16) = accS[mt];

    if (g + 1 < NGRP - 1) {
      __syncthreads();
#pragma unroll
      for (int mt = 0; mt < 4; ++mt)
        *(f32x4*)(&sl[n * 68 + mt * 16 + q * 4]) = accS[mt];
      __syncthreads();
#pragma unroll
      for (int ks = 0; ks < 2; ++ks) {
        f32x4 s0 = *(const f32x4*)(&sl[n * 68 + ks * 32 + q * 8]);
        f32x4 s1 = *(const f32x4*)(&sl[n * 68 + ks * 32 + q * 8 + 4]);
#pragma unroll
        for (int j = 0; j < 4; ++j) {
          u16 hh, ll;
          split2(s0[j], hh, ll);
          Sbh[ks][j] = (short)hh; Sbl[ks][j] = (short)ll;
          split2(s1[j], hh, ll);
          Sbh[ks][j + 4] = (short)hh; Sbl[ks][j + 4] = (short)ll;
        }
      }
    }

    ec[0] = en[0]; ec[1] = en[1]; ec[2] = en[2]; ec[3] = en[3];
  }
}

// Main scan: per (rowgroup,superchunk) wave, start from sg_g, GLEN chunks.
__global__ void __launch_bounds__(256, 2)
ssm_scan_mfma(const float* __restrict__ ws, const float* __restrict__ v,
              float* __restrict__ y) {
  __shared__ float SL[4][16 * 68];
  const int lane = threadIdx.x & 63;
  const int n = lane & 15, q = lane >> 4;
  const int wid = blockIdx.x * 4 + (threadIdx.x >> 6);
  const int R = (wid >> 4) * 16;
  const int g = wid & 15;
  float* sl = SL[threadIdx.x >> 6];

  const unsigned short* ph  = (const unsigned short*)(ws + WS_PH);
  const unsigned short* pll = (const unsigned short*)(ws + WS_PL);
  const unsigned short* a1h = (const unsigned short*)(ws + WS_A1H);
  const unsigned short* a1l = (const unsigned short*)(ws + WS_A1L);

  bf16x8 Ph[4][2], Pl[4][2], Ah[4][2], Al[4][2];
#pragma unroll
  for (int mt = 0; mt < 4; ++mt)
#pragma unroll
    for (int ks = 0; ks < 2; ++ks) {
      int off = (mt * 16 + n) * 64 + ks * 32 + q * 8;
      Ph[mt][ks] = *(const bf16x8*)(ph + off);
      Pl[mt][ks] = *(const bf16x8*)(pll + off);
      Ah[mt][ks] = *(const bf16x8*)(a1h + off);
      Al[mt][ks] = *(const bf16x8*)(a1l + off);
    }

  bf16x8 Sbh[2], Sbl[2];
  {
    const float* sgp = ws + WS_SG + ((size_t)(R + n) * NGRP + g) * 64;
#pragma unroll
    for (int ks = 0; ks < 2; ++ks) {
      f32x4 s0 = *(const f32x4*)(sgp + ks * 32 + q * 8);
      f32x4 s1 = *(const f32x4*)(sgp + ks * 32 + q * 8 + 4);
#pragma unroll
      for (int j = 0; j < 4; ++j) {
        u16 hh, ll;
        split2(s0[j], hh, ll);
        Sbh[ks][j] = (short)hh; Sbl[ks][j] = (short)ll;
        split2(s1[j], hh, ll);
        Sbh[ks][j + 4] = (short)hh; Sbl[ks][j + 4] = (short)ll;
      }
    }
  }

  const int cb = g * GLEN;
  const float* vrow = v + ((size_t)(R + n) * NCHUNK) * 64 + q * 4;
  float*       yrow = y + (size_t)(R + n) * LSEQ + q * 4;

  f32x4 vc[4], yc[4];
#pragma unroll
  for (int mt = 0; mt < 4; ++mt) {
    vc[mt] = *(const f32x4*)(vrow + (size_t)cb * 64 + mt * 16);
    yc[mt] = *(const f32x4*)(yrow + (size_t)cb * 64 + mt * 16);
  }

  for (int c8 = 0; c8 < GLEN; ++c8) {
    const int c = cb + c8;
    const int cn = cb + ((c8 + 1 < GLEN) ? (c8 + 1) : c8);
    f32x4 vn[4], yn[4];
#pragma unroll
    for (int mt = 0; mt < 4; ++mt) {
      vn[mt] = *(const f32x4*)(vrow + (size_t)cn * 64 + mt * 16);
      yn[mt] = *(const f32x4*)(yrow + (size_t)cn * 64 + mt * 16);
    }

    f32x4 accS[4], accY[4];
#pragma unroll
    for (int mt = 0; mt < 4; ++mt) {
      f32x4 as = vc[mt];
      as = __builtin_amdgcn_mfma_f32_16x16x32_bf16(Ph[mt][0], Sbh[0], as, 0, 0, 0);
      as = __builtin_amdgcn_mfma_f32_16x16x32_bf16(Ph[mt][1], Sbh[1], as, 0, 0, 0);
      as = __builtin_amdgcn_mfma_f32_16x16x32_bf16(Ph[mt][0], Sbl[0], as, 0, 0, 0);
      as = __builtin_amdgcn_mfma_f32_16x16x32_bf16(Ph[mt][1], Sbl[1], as, 0, 0, 0);
      as = __builtin_amdgcn_mfma_f32_16x16x32_bf16(Pl[mt][0], Sbh[0], as, 0, 0, 0);
      as = __builtin_amdgcn_mfma_f32_16x16x32_bf16(Pl[mt][1], Sbh[1], as, 0, 0, 0);
      accS[mt] = as;
      f32x4 ay = yc[mt];
      ay = __builtin_amdgcn_mfma_f32_16x16x32_bf16(Ah[mt][0], Sbh[0], ay, 0, 0, 0);
      ay = __builtin_amdgcn_mfma_f32_16x16x32_bf16(Ah[mt][1], Sbh[1], ay, 0, 0, 0);
      ay = __builtin_amdgcn_mfma_f32_16x16x32_bf16(Ah[mt][0], Sbl[0], ay, 0, 0, 0);
      ay = __builtin_amdgcn_mfma_f32_16x16x32_bf16(Ah[mt][1], Sbl[1], ay, 0, 0, 0);
      ay = __builtin_amdgcn_mfma_f32_16x16x32_bf16(Al[mt][0], Sbh[0], ay, 0, 0, 0);
      ay = __builtin_amdgcn_mfma_f32_16x16x32_bf16(Al[mt][1], Sbh[1], ay, 0, 0, 0);
      accY[mt] = ay;
    }

#pragma unroll
    for (int mt = 0; mt < 4; ++mt)
      *(f32x4*)(yrow + (size_t)c * 64 + mt * 16) = accY[mt];

    if (c8 + 1 < GLEN) {
      __syncthreads();
#pragma unroll
      for (int mt = 0; mt < 4; ++mt)
        *(f32x4*)(&sl[n * 68 + mt * 16 + q * 4]) = accS[mt];
      __syncthreads();
#pragma unroll
      for (int ks = 0; ks < 2; ++ks) {
        f32x4 s0 = *(const f32x4*)(&sl[n * 68 + ks * 32 + q * 8]);
        f32x4 s1 = *(const f32x4*)(&sl[n * 68 + ks * 32 + q * 8 + 4]);
#pragma unroll
        for (int j = 0; j < 4; ++j) {
          u16 hh, ll;
          split2(s0[j], hh, ll);
          Sbh[ks][j] = (short)hh; Sbl[ks][j] = (short)ll;
          split2(s1[j], hh, ll);
          Sbh[ks][j + 4] = (short)hh; Sbl[ks][j + 4] = (short)ll;
        }
      }
    }

    vc[0] = vn[0]; vc[1] = vn[1]; vc[2] = vn[2]; vc[3] = vn[3];
    yc[0] = yn[0]; yc[1] = yn[1]; yc[2] = yn[2]; yc[3] = yn[3];
  }
}

extern "C" void kernel_launch(void* const* d_in, const int* in_sizes, int n_in,
                              void* d_out, int out_size, void* d_ws, size_t ws_size,
                              hipStream_t stream) {
  const float* u  = (const float*)d_in[0];
  const float* A  = (const float*)d_in[1];
  const float* B  = (const float*)d_in[2];
  const float* C  = (const float*)d_in[3];
  const float* D  = (const float*)d_in[4];
  const float* ls = (const float*)d_in[5];
  float* ws  = (float*)d_ws;
  float* out = (float*)d_out;
  float* v   = ws + WS_V;

  ssm_pre<<<dim3(1), dim3(1024), 0, stream>>>(A, B, C, D, ls, ws);
  ssm_conv_mfma<<<dim3(1024), dim3(256), 0, stream>>>(u, ws, out, v);
  ssm_scan_e<<<dim3(512), dim3(256), 0, stream>>>(ws, v);
  ssm_scan_sg<<<dim3(32), dim3(256), 0, stream>>>(ws);
  ssm_scan_mfma<<<dim3(512), dim3(256), 0, stream>>>(ws, v, out);
}

// Round 5
// 218.490 us; speedup vs baseline: 1.6661x; 1.2025x over previous
//
#include <hip/hip_runtime.h>
#include <math.h>

#define LSEQ   8192
#define CHUNK  64
#define NCHUNK 128
#define NBATCH 2048
#define NGRP   16      /* superchunks */
#define GLEN   8       /* chunks per superchunk: NGRP*GLEN == NCHUNK */

// ws float layout (v slot retained but unused since round 5):
#define WS_V   0
#define T0     (NBATCH * NCHUNK * 64)
#define WS_P   (T0)
#define WS_A1  (T0 + 4096)
#define WS_K   (T0 + 8192)
#define WS_WH  (T0 + 8256)    /* 4096 floats = 8192 bf16: W hi, row-major 128x64 */
#define WS_WL  (T0 + 12352)   /* 4096 floats: W lo */
#define WS_PH  (T0 + 16448)   /* 2048 floats = 4096 bf16: P hi, row-major 64x64 */
#define WS_PL  (T0 + 18496)
#define WS_A1H (T0 + 20544)
#define WS_A1L (T0 + 22592)
#define WS_P8H (T0 + 24640)
#define WS_P8L (T0 + 26688)
#define WS_E   (T0 + 28736)                 /* NBATCH*NGRP*64 = 2097152 floats */
#define WS_SG  (WS_E + NBATCH * NGRP * 64)  /* same size */

typedef short bf16x8 __attribute__((ext_vector_type(8)));
typedef float f32x4  __attribute__((ext_vector_type(4)));
typedef unsigned short u16;

__device__ __forceinline__ u16 bf16rne(float x) {
  unsigned b = __builtin_bit_cast(unsigned, x);
  return (u16)((b + 0x7fffu + ((b >> 16) & 1u)) >> 16);
}
__device__ __forceinline__ float bf2f(u16 h) {
  return __builtin_bit_cast(float, ((unsigned)h) << 16);
}
__device__ __forceinline__ void split2(float x, u16& h, u16& l) {
  h = bf16rne(x);
  l = bf16rne(x - bf2f(h));
}
__device__ __forceinline__ void split3(float x, u16& h, u16& m, u16& l) {
  h = bf16rne(x);
  float r = x - bf2f(h);
  m = bf16rne(r);
  r -= bf2f(m);
  l = bf16rne(r);
}

// XOR swizzle on 8-col groups: kills the stride-128B same-bank pattern for
// ds_read_b128 fragment reads (G4/T2). Used by pre's LDS matrices and the
// main kernel's staged W/A1 tables.
__device__ __forceinline__ int swz(int r, int c) {
  return r * 64 + (c ^ ((r & 7) << 3));
}
__device__ __forceinline__ float tri_get(const u16* p, int r, int c) {
  const int e = swz(r, c);
  return bf2f(p[e]) + bf2f(p[4096 + e]) + bf2f(p[8192 + e]);
}

// ---------------- pre: MFMA triple-bf16 64x64 matmuls (round-4, verified) ----
__device__ __forceinline__ void mfma_tile3(
    const u16* __restrict__ A3, const u16* __restrict__ B3, u16* __restrict__ D3,
    int mt, int nt, int aShift,
    const u16* add1, const u16* add2, int addI, int rLo, int rHi) {
  const int lane = threadIdx.x & 63;
  const int n = lane & 15, q = lane >> 4;
  int ar = mt * 16 + n - aShift;
  ar = ar < 0 ? 0 : (ar > 63 ? 63 : ar);
  const int bc = nt * 16 + n;
  bf16x8 ah[2], am[2], al[2], bh[2], bm[2], bl[2];
#pragma unroll
  for (int ks = 0; ks < 2; ++ks) {
    const int ao = swz(ar, ks * 32 + q * 8);
    const int bo = swz(bc, ks * 32 + q * 8);
    ah[ks] = *(const bf16x8*)(A3 + ao);
    am[ks] = *(const bf16x8*)(A3 + 4096 + ao);
    al[ks] = *(const bf16x8*)(A3 + 8192 + ao);
    bh[ks] = *(const bf16x8*)(B3 + bo);
    bm[ks] = *(const bf16x8*)(B3 + 4096 + bo);
    bl[ks] = *(const bf16x8*)(B3 + 8192 + bo);
  }
  f32x4 acc = {0.f, 0.f, 0.f, 0.f};
#define MF(a, b) acc = __builtin_amdgcn_mfma_f32_16x16x32_bf16(a, b, acc, 0, 0, 0)
  MF(ah[0], bh[0]); MF(ah[1], bh[1]);
  MF(ah[0], bm[0]); MF(ah[1], bm[1]);
  MF(am[0], bh[0]); MF(am[1], bh[1]);
  MF(ah[0], bl[0]); MF(ah[1], bl[1]);
  MF(am[0], bm[0]); MF(am[1], bm[1]);
  MF(al[0], bh[0]); MF(al[1], bh[1]);
#undef MF
#pragma unroll
  for (int j = 0; j < 4; ++j) {
    const int i = mt * 16 + q * 4 + j, c = nt * 16 + n;
    float v = acc[j];
    if (add1) v += tri_get(add1, i, c);
    if (add2) v += tri_get(add2, i, c);
    if (addI && i == c) v += 1.f;
    if (i >= rLo && i < rHi) {
      u16 h3, m3, l3; split3(v, h3, m3, l3);
      const int e = swz(i, c);
      D3[e] = h3; D3[4096 + e] = m3; D3[8192 + e] = l3;
    }
  }
}

__device__ __forceinline__ void pair_phase(
    const u16* Pf, const u16* Qt, u16* Fn, u16* Tn,
    const u16* addF1, const u16* addT1, int addI) {
  __syncthreads();
  const int w = threadIdx.x >> 6;
#pragma unroll
  for (int tix = w; tix < 32; tix += 16) {
    if (tix < 16) mfma_tile3(Pf, Qt, Fn, tix >> 2, tix & 3, 0, addF1, 0, addI, 0, 64);
    else { const int s = tix - 16; mfma_tile3(Qt, Pf, Tn, s >> 2, s & 3, 0, addT1, 0, addI, 0, 64); }
  }
}
__device__ __forceinline__ void single_phase(
    const u16* A3, const u16* B3, u16* D3,
    const u16* add1, const u16* add2, int addI) {
  __syncthreads();
  const int w = threadIdx.x >> 6;
  mfma_tile3(A3, B3, D3, w >> 2, w & 3, 0, add1, add2, addI, 0, 64);
}

__global__ void __launch_bounds__(1024)
ssm_pre(const float* __restrict__ Ag, const float* __restrict__ Bg,
        const float* __restrict__ Cg, const float* __restrict__ Dg,
        const float* __restrict__ lsg, float* __restrict__ ws) {
  __shared__ __attribute__((aligned(16))) u16 TRI[6][3 * 4096];
  __shared__ float Kl[64];
  u16* tri0 = TRI[0]; u16* tri1 = TRI[1]; u16* tri2 = TRI[2];
  u16* tri3 = TRI[3]; u16* tri4 = TRI[4]; u16* tri5 = TRI[5];

  const int t = threadIdx.x;
  const int w = t >> 6;
  const float step = expf(lsg[0]);
  const float hstep = 0.5f * step;
  const float D0 = Dg[0];

  float* Xf = (float*)tri2;
  for (int e = t; e < 4096; e += 1024) {
    const float x = hstep * Ag[e];
    Xf[e] = x;
    u16 h3, m3, l3; split3(x, h3, m3, l3);
    const int s = swz(e >> 6, e & 63);
    tri0[s] = h3; tri0[4096 + s] = m3; tri0[8192 + s] = l3;
  }
  __syncthreads();
  for (int e = t; e < 4096; e += 1024) {
    const int r = e >> 6, c = e & 63;
    const float x = Xf[c * 64 + r];
    u16 h3, m3, l3; split3(x, h3, m3, l3);
    const int s = swz(r, c);
    tri1[s] = h3; tri1[4096 + s] = m3; tri1[8192 + s] = l3;
  }
  pair_phase(tri0, tri1, tri2, tri3, 0, 0, 0);          // X2
  pair_phase(tri2, tri3, tri4, tri5, 0, 0, 0);          // X4
  single_phase(tri4, tri3, tri0, tri4, tri2, 1);        // T1
  single_phase(tri3, tri4, tri2, tri3, tri5, 1);        // T1T
  pair_phase(tri0, tri1, tri3, tri5, tri0, tri2, 0);    // BL / BLT
  pair_phase(tri3, tri1, tri4, tri2, tri3, tri5, 0);    // Ab / AbT

  __syncthreads();
  if (t < 64) {
    float acc = 0.f;
    for (int m = 0; m < 64; ++m) acc += tri_get(tri3, t, m) * Bg[m];  // BL row t
    const float bb = step * acc;
    u16 h3, m3, l3; split3(bb, h3, m3, l3);
    const int s = swz(0, t);
    tri0[s] = h3; tri0[4096 + s] = m3; tri0[8192 + s] = l3;
  } else if (t < 128) {
    const int r = t - 64;
    float acc = 0.f;
    for (int m = 0; m < 64; ++m) acc += tri_get(tri2, r, m) * Cg[m];  // AbT row r
    u16 h3, m3, l3; split3(acc, h3, m3, l3);
    const int s = swz(0, r);
    tri1[s] = h3; tri1[4096 + s] = m3; tri1[8192 + s] = l3;
  }

  u16 *curF = tri4, *curT = tri2, *nxtF = tri3, *nxtT = tri5;
  for (int k = 1; k <= 32; k <<= 1) {
    __syncthreads();
    const int mtLo = k >> 4, mtHi = (2 * k - 1) >> 4;
    const int cnt = (mtHi - mtLo + 1) * 4;
    const int total = 32 + 2 * cnt;
    for (int tix = w; tix < total; tix += 16) {
      if (tix < 16) {
        mfma_tile3(curF, curT, nxtF, tix >> 2, tix & 3, 0, 0, 0, 0, 0, 64);
      } else if (tix < 32) {
        const int s = tix - 16;
        mfma_tile3(curT, curF, nxtT, s >> 2, s & 3, 0, 0, 0, 0, 0, 64);
      } else if (tix < 32 + cnt) {
        const int s = tix - 32;
        mfma_tile3(tri0, curF, tri0, mtLo + (s >> 2), s & 3, k, 0, 0, 0, k, 2 * k);
      } else {
        const int s = tix - 32 - cnt;
        mfma_tile3(tri1, curT, tri1, mtLo + (s >> 2), s & 3, k, 0, 0, 0, k, 2 * k);
      }
    }
    u16* tmp;
    tmp = curF; curF = nxtF; nxtF = tmp;
    tmp = curT; curT = nxtT; nxtT = tmp;
  }

  __syncthreads();
  float* wsP  = ws + WS_P;
  float* wsA1 = ws + WS_A1;
  u16* ph  = (u16*)(ws + WS_PH);
  u16* pl  = (u16*)(ws + WS_PL);
  u16* a1h = (u16*)(ws + WS_A1H);
  u16* a1l = (u16*)(ws + WS_A1L);
  u16* p8h = (u16*)(ws + WS_P8H);
  u16* p8l = (u16*)(ws + WS_P8L);
  for (int e = t; e < 4096; e += 1024) {
    const float x = tri_get(curF, e >> 6, e & 63);
    wsP[e] = x;
    u16 hh, ll; split2(x, hh, ll); ph[e] = hh; pl[e] = ll;
  }
  for (int r2 = 0; r2 < 3; ++r2) {
    pair_phase(curF, curT, nxtF, nxtT, 0, 0, 0);
    u16* tmp;
    tmp = curF; curF = nxtF; nxtF = tmp;
    tmp = curT; curT = nxtT; nxtT = tmp;
  }
  __syncthreads();
  for (int e = t; e < 4096; e += 1024) {
    const int r = e >> 6, c = e & 63;
    float x = tri_get(curF, r, c);
    u16 hh, ll; split2(x, hh, ll); p8h[e] = hh; p8l[e] = ll;
    const float a1v = tri_get(tri1, r, c);
    wsA1[e] = a1v;
    split2(a1v, hh, ll); a1h[e] = hh; a1l[e] = ll;
  }
  if (t < 64) {
    float acc = 0.f;
    for (int m = 0; m < 64; ++m) acc += Cg[m] * tri_get(tri0, t, m);
    Kl[t] = acc;
  }
  __syncthreads();
  u16* wh = (u16*)(ws + WS_WH);
  u16* wl = (u16*)(ws + WS_WL);
  for (int e = t; e < 8192; e += 1024) {
    const int i = e >> 6, j = e & 63;
    float wv;
    if (i < 64) wv = ((i >= j) ? Kl[i - j] : 0.f) + ((i == j) ? D0 : 0.f);
    else        wv = tri_get(tri0, 63 - j, i - 64);   // gB[m][jj] = gBT[jj][m]
    u16 hh, ll; split2(wv, hh, ll);
    wh[e] = hh;
    wl[e] = ll;
  }
}

// -------- fused scan: conv eliminated; v computed on the fly from u ---------
// Wave = rowgroup R (16 rows) x superchunk g (8 chunks).
// B-frag for u: lane(n,q) holds u[R+n][c*64 + ks*32+q*8+j] - direct loads.
// v = Wbot@u (24 MFMA); IDENTICAL MFMA sequence in scan_e and scan_main so
// both compute bitwise-equal v (required: E/SG and the main trajectory must
// agree). Fragment mappings as before.

// E-kernel: read u, local scan from s=0 -> E_g. Wbot + P in VGPR (~208).
__global__ void __launch_bounds__(256, 2)
ssm_scan_e(float* __restrict__ ws, const float* __restrict__ u) {
  __shared__ float SL[4][16 * 68];
  const int lane = threadIdx.x & 63;
  const int n = lane & 15, q = lane >> 4;
  const int wid = blockIdx.x * 4 + (threadIdx.x >> 6);
  const int R = (wid >> 4) * 16;
  const int g = wid & 15;
  float* sl = SL[threadIdx.x >> 6];

  const u16* ph = (const u16*)(ws + WS_PH);
  const u16* pl = (const u16*)(ws + WS_PL);
  const u16* wh = (const u16*)(ws + WS_WH);
  const u16* wl = (const u16*)(ws + WS_WL);
  bf16x8 Ph[4][2], Pl[4][2], Wbh[4][2], Wbl[4][2];
#pragma unroll
  for (int mt = 0; mt < 4; ++mt)
#pragma unroll
    for (int ks = 0; ks < 2; ++ks) {
      const int off  = (mt * 16 + n) * 64 + ks * 32 + q * 8;
      const int offb = off + 64 * 64;             // Wbot rows 64..127
      Ph[mt][ks]  = *(const bf16x8*)(ph + off);
      Pl[mt][ks]  = *(const bf16x8*)(pl + off);
      Wbh[mt][ks] = *(const bf16x8*)(wh + offb);
      Wbl[mt][ks] = *(const bf16x8*)(wl + offb);
    }

  bf16x8 Sbh[2], Sbl[2];
#pragma unroll
  for (int ks = 0; ks < 2; ++ks)
#pragma unroll
    for (int j = 0; j < 8; ++j) { Sbh[ks][j] = 0; Sbl[ks][j] = 0; }

  const int cb = g * GLEN;
  const float* ub = u + (size_t)(R + n) * LSEQ + cb * 64 + q * 8;

  f32x4 f0 = *(const f32x4*)(ub);
  f32x4 f1 = *(const f32x4*)(ub + 4);
  f32x4 f2 = *(const f32x4*)(ub + 32);
  f32x4 f3 = *(const f32x4*)(ub + 36);

  for (int c8 = 0; c8 < GLEN; ++c8) {
    // split current chunk's u to bf16 hi/lo B-frags
    bf16x8 ubh[2], ubl[2];
    {
      float xs0[8] = {f0[0], f0[1], f0[2], f0[3], f1[0], f1[1], f1[2], f1[3]};
      float xs1[8] = {f2[0], f2[1], f2[2], f2[3], f3[0], f3[1], f3[2], f3[3]};
#pragma unroll
      for (int j = 0; j < 8; ++j) {
        u16 hh, ll;
        split2(xs0[j], hh, ll); ubh[0][j] = (short)hh; ubl[0][j] = (short)ll;
        split2(xs1[j], hh, ll); ubh[1][j] = (short)hh; ubl[1][j] = (short)ll;
      }
    }
    // prefetch next chunk
    const int cn = (c8 + 1 < GLEN) ? (c8 + 1) : c8;
    const float* nb = ub + cn * 64;
    f0 = *(const f32x4*)(nb);
    f1 = *(const f32x4*)(nb + 4);
    f2 = *(const f32x4*)(nb + 32);
    f3 = *(const f32x4*)(nb + 36);

    f32x4 accS[4];
#pragma unroll
    for (int mt = 0; mt < 4; ++mt) {
      f32x4 as = {0.f, 0.f, 0.f, 0.f};
#define MF(a, b) as = __builtin_amdgcn_mfma_f32_16x16x32_bf16(a, b, as, 0, 0, 0)
      MF(Wbh[mt][0], ubh[0]); MF(Wbh[mt][1], ubh[1]);      // v = Wbot@u
      MF(Wbh[mt][0], ubl[0]); MF(Wbh[mt][1], ubl[1]);
      MF(Wbl[mt][0], ubh[0]); MF(Wbl[mt][1], ubh[1]);
      MF(Ph[mt][0], Sbh[0]);  MF(Ph[mt][1], Sbh[1]);       // + P@S
      MF(Ph[mt][0], Sbl[0]);  MF(Ph[mt][1], Sbl[1]);
      MF(Pl[mt][0], Sbh[0]);  MF(Pl[mt][1], Sbh[1]);
#undef MF
      accS[mt] = as;
    }

    if (c8 + 1 < GLEN) {
      __syncthreads();
#pragma unroll
      for (int mt = 0; mt < 4; ++mt)
        *(f32x4*)(&sl[n * 68 + mt * 16 + q * 4]) = accS[mt];
      __syncthreads();
#pragma unroll
      for (int ks = 0; ks < 2; ++ks) {
        f32x4 s0 = *(const f32x4*)(&sl[n * 68 + ks * 32 + q * 8]);
        f32x4 s1 = *(const f32x4*)(&sl[n * 68 + ks * 32 + q * 8 + 4]);
#pragma unroll
        for (int j = 0; j < 4; ++j) {
          u16 hh, ll;
          split2(s0[j], hh, ll); Sbh[ks][j] = (short)hh; Sbl[ks][j] = (short)ll;
          split2(s1[j], hh, ll); Sbh[ks][j + 4] = (short)hh; Sbl[ks][j + 4] = (short)ll;
        }
      }
    } else {
      float* eb = ws + WS_E + ((size_t)(R + n) * NGRP + g) * 64 + q * 4;
#pragma unroll
      for (int mt = 0; mt < 4; ++mt)
        *(f32x4*)(eb + mt * 16) = accS[mt];
    }
  }
}

// sigma-kernel: per row-group boundary scan sg_{g+1} = P8@sg_g + E_g (as-is).
__global__ void __launch_bounds__(256, 2)
ssm_scan_sg(float* __restrict__ ws) {
  __shared__ float SL[4][16 * 68];
  const int lane = threadIdx.x & 63;
  const int n = lane & 15, q = lane >> 4;
  const int wid = blockIdx.x * 4 + (threadIdx.x >> 6);
  const int R = wid * 16;
  float* sl = SL[threadIdx.x >> 6];

  const u16* p8h = (const u16*)(ws + WS_P8H);
  const u16* p8l = (const u16*)(ws + WS_P8L);
  bf16x8 Ph[4][2], Pl[4][2];
#pragma unroll
  for (int mt = 0; mt < 4; ++mt)
#pragma unroll
    for (int ks = 0; ks < 2; ++ks) {
      int off = (mt * 16 + n) * 64 + ks * 32 + q * 8;
      Ph[mt][ks] = *(const bf16x8*)(p8h + off);
      Pl[mt][ks] = *(const bf16x8*)(p8l + off);
    }

  bf16x8 Sbh[2], Sbl[2];
#pragma unroll
  for (int ks = 0; ks < 2; ++ks)
#pragma unroll
    for (int j = 0; j < 8; ++j) { Sbh[ks][j] = 0; Sbl[ks][j] = 0; }

  const float* erow = ws + WS_E + ((size_t)(R + n) * NGRP) * 64 + q * 4;
  float*       srow = ws + WS_SG + ((size_t)(R + n) * NGRP) * 64 + q * 4;

  {
    f32x4 z = {0.f, 0.f, 0.f, 0.f};
#pragma unroll
    for (int mt = 0; mt < 4; ++mt) *(f32x4*)(srow + mt * 16) = z;
  }

  f32x4 ec[4];
#pragma unroll
  for (int mt = 0; mt < 4; ++mt) ec[mt] = *(const f32x4*)(erow + mt * 16);

  for (int g = 0; g < NGRP - 1; ++g) {
    const int gn = (g + 1 < NGRP - 1) ? (g + 1) : g;
    f32x4 en[4];
#pragma unroll
    for (int mt = 0; mt < 4; ++mt)
      en[mt] = *(const f32x4*)(erow + (size_t)gn * 64 + mt * 16);

    f32x4 accS[4];
#pragma unroll
    for (int mt = 0; mt < 4; ++mt) {
      f32x4 as = ec[mt];
#define MF(a, b) as = __builtin_amdgcn_mfma_f32_16x16x32_bf16(a, b, as, 0, 0, 0)
      MF(Ph[mt][0], Sbh[0]); MF(Ph[mt][1], Sbh[1]);
      MF(Ph[mt][0], Sbl[0]); MF(Ph[mt][1], Sbl[1]);
      MF(Pl[mt][0], Sbh[0]); MF(Pl[mt][1], Sbh[1]);
#undef MF
      accS[mt] = as;
    }

#pragma unroll
    for (int mt = 0; mt < 4; ++mt)
      *(f32x4*)(srow + (size_t)(g + 1) * 64 + mt * 16) = accS[mt];

    if (g + 1 < NGRP - 1) {
      __syncthreads();
#pragma unroll
      for (int mt = 0; mt < 4; ++mt)
        *(f32x4*)(&sl[n * 68 + mt * 16 + q * 4]) = accS[mt];
      __syncthreads();
#pragma unroll
      for (int ks = 0; ks < 2; ++ks) {
        f32x4 s0 = *(const f32x4*)(&sl[n * 68 + ks * 32 + q * 8]);
        f32x4 s1 = *(const f32x4*)(&sl[n * 68 + ks * 32 + q * 8 + 4]);
#pragma unroll
        for (int j = 0; j < 4; ++j) {
          u16 hh, ll;
          split2(s0[j], hh, ll); Sbh[ks][j] = (short)hh; Sbl[ks][j] = (short)ll;
          split2(s1[j], hh, ll); Sbh[ks][j + 4] = (short)hh; Sbl[ks][j + 4] = (short)ll;
        }
      }
    }

    ec[0] = en[0]; ec[1] = en[1]; ec[2] = en[2]; ec[3] = en[3];
  }
}

// Main fused kernel: read u + SG, compute y0=Wtop@u, y=y0+A1@S_old, and the
// S recurrence with on-the-fly v=Wbot@u. P + Wbot in VGPR; Wtop + A1 staged
// swizzled in LDS (ds_read_b128 per chunk, off the critical S-chain).
__global__ void __launch_bounds__(256, 2)
ssm_scan_main(const float* __restrict__ ws, const float* __restrict__ u,
              float* __restrict__ y) {
  __shared__ float SL[4][16 * 68];
  __shared__ __attribute__((aligned(16))) u16 WT[2][4096];   // Wtop hi/lo, swizzled
  __shared__ __attribute__((aligned(16))) u16 A1S[2][4096];  // A1  hi/lo, swizzled
  const int lane = threadIdx.x & 63;
  const int n = lane & 15, q = lane >> 4;
  const int wid = blockIdx.x * 4 + (threadIdx.x >> 6);
  const int R = (wid >> 4) * 16;
  const int g = wid & 15;
  float* sl = SL[threadIdx.x >> 6];

  // stage Wtop + A1 into LDS (swizzled)
  {
    const u16* whg  = (const u16*)(ws + WS_WH);
    const u16* wlg  = (const u16*)(ws + WS_WL);
    const u16* a1hg = (const u16*)(ws + WS_A1H);
    const u16* a1lg = (const u16*)(ws + WS_A1L);
    for (int e = threadIdx.x; e < 4096; e += 256) {
      const int s = swz(e >> 6, e & 63);
      WT[0][s]  = whg[e];  WT[1][s]  = wlg[e];
      A1S[0][s] = a1hg[e]; A1S[1][s] = a1lg[e];
    }
  }

  const u16* ph = (const u16*)(ws + WS_PH);
  const u16* pl = (const u16*)(ws + WS_PL);
  const u16* wh = (const u16*)(ws + WS_WH);
  const u16* wl = (const u16*)(ws + WS_WL);
  bf16x8 Ph[4][2], Pl[4][2], Wbh[4][2], Wbl[4][2];
#pragma unroll
  for (int mt = 0; mt < 4; ++mt)
#pragma unroll
    for (int ks = 0; ks < 2; ++ks) {
      const int off  = (mt * 16 + n) * 64 + ks * 32 + q * 8;
      const int offb = off + 64 * 64;
      Ph[mt][ks]  = *(const bf16x8*)(ph + off);
      Pl[mt][ks]  = *(const bf16x8*)(pl + off);
      Wbh[mt][ks] = *(const bf16x8*)(wh + offb);
      Wbl[mt][ks] = *(const bf16x8*)(wl + offb);
    }

  // S init from sg_g
  bf16x8 Sbh[2], Sbl[2];
  {
    const float* sgp = ws + WS_SG + ((size_t)(R + n) * NGRP + g) * 64;
#pragma unroll
    for (int ks = 0; ks < 2; ++ks) {
      f32x4 s0 = *(const f32x4*)(sgp + ks * 32 + q * 8);
      f32x4 s1 = *(const f32x4*)(sgp + ks * 32 + q * 8 + 4);
#pragma unroll
      for (int j = 0; j < 4; ++j) {
        u16 hh, ll;
        split2(s0[j], hh, ll); Sbh[ks][j] = (short)hh; Sbl[ks][j] = (short)ll;
        split2(s1[j], hh, ll); Sbh[ks][j + 4] = (short)hh; Sbl[ks][j + 4] = (short)ll;
      }
    }
  }

  const int cb = g * GLEN;
  const float* ub = u + (size_t)(R + n) * LSEQ + cb * 64 + q * 8;
  float*     yrow = y + (size_t)(R + n) * LSEQ + q * 4;

  f32x4 f0 = *(const f32x4*)(ub);
  f32x4 f1 = *(const f32x4*)(ub + 4);
  f32x4 f2 = *(const f32x4*)(ub + 32);
  f32x4 f3 = *(const f32x4*)(ub + 36);

  __syncthreads();   // staging visible

  for (int c8 = 0; c8 < GLEN; ++c8) {
    const int c = cb + c8;
    bf16x8 ubh[2], ubl[2];
    {
      float xs0[8] = {f0[0], f0[1], f0[2], f0[3], f1[0], f1[1], f1[2], f1[3]};
      float xs1[8] = {f2[0], f2[1], f2[2], f2[3], f3[0], f3[1], f3[2], f3[3]};
#pragma unroll
      for (int j = 0; j < 8; ++j) {
        u16 hh, ll;
        split2(xs0[j], hh, ll); ubh[0][j] = (short)hh; ubl[0][j] = (short)ll;
        split2(xs1[j], hh, ll); ubh[1][j] = (short)hh; ubl[1][j] = (short)ll;
      }
    }
    const int cn = (c8 + 1 < GLEN) ? (c8 + 1) : c8;
    const float* nb = ub + cn * 64;
    f0 = *(const f32x4*)(nb);
    f1 = *(const f32x4*)(nb + 4);
    f2 = *(const f32x4*)(nb + 32);
    f3 = *(const f32x4*)(nb + 36);

    // accY = Wtop@u + A1@S_old   (frags streamed from LDS)
#pragma unroll
    for (int mt = 0; mt < 4; ++mt) {
      f32x4 ay = {0.f, 0.f, 0.f, 0.f};
      const int o0 = swz(mt * 16 + n, q * 8);
      const int o1 = swz(mt * 16 + n, 32 + q * 8);
      bf16x8 th0 = *(const bf16x8*)(&WT[0][o0]);
      bf16x8 th1 = *(const bf16x8*)(&WT[0][o1]);
      bf16x8 tl0 = *(const bf16x8*)(&WT[1][o0]);
      bf16x8 tl1 = *(const bf16x8*)(&WT[1][o1]);
#define MF(a, b) ay = __builtin_amdgcn_mfma_f32_16x16x32_bf16(a, b, ay, 0, 0, 0)
      MF(th0, ubh[0]); MF(th1, ubh[1]);
      MF(th0, ubl[0]); MF(th1, ubl[1]);
      MF(tl0, ubh[0]); MF(tl1, ubh[1]);
      bf16x8 ah0 = *(const bf16x8*)(&A1S[0][o0]);
      bf16x8 ah1 = *(const bf16x8*)(&A1S[0][o1]);
      bf16x8 al0 = *(const bf16x8*)(&A1S[1][o0]);
      bf16x8 al1 = *(const bf16x8*)(&A1S[1][o1]);
      MF(ah0, Sbh[0]); MF(ah1, Sbh[1]);
      MF(ah0, Sbl[0]); MF(ah1, Sbl[1]);
      MF(al0, Sbh[0]); MF(al1, Sbh[1]);
#undef MF
      *(f32x4*)(yrow + (size_t)c * 64 + mt * 16) = ay;
    }

    // S' = P@S + v  (skip on superchunk-final chunk: S' unused)
    if (c8 + 1 < GLEN) {
      f32x4 accS[4];
#pragma unroll
      for (int mt = 0; mt < 4; ++mt) {
        f32x4 as = {0.f, 0.f, 0.f, 0.f};
#define MF(a, b) as = __builtin_amdgcn_mfma_f32_16x16x32_bf16(a, b, as, 0, 0, 0)
        MF(Wbh[mt][0], ubh[0]); MF(Wbh[mt][1], ubh[1]);    // v  (identical order
        MF(Wbh[mt][0], ubl[0]); MF(Wbh[mt][1], ubl[1]);    //    to ssm_scan_e)
        MF(Wbl[mt][0], ubh[0]); MF(Wbl[mt][1], ubh[1]);
        MF(Ph[mt][0], Sbh[0]);  MF(Ph[mt][1], Sbh[1]);
        MF(Ph[mt][0], Sbl[0]);  MF(Ph[mt][1], Sbl[1]);
        MF(Pl[mt][0], Sbh[0]);  MF(Pl[mt][1], Sbh[1]);
#undef MF
        accS[mt] = as;
      }
      __syncthreads();
#pragma unroll
      for (int mt = 0; mt < 4; ++mt)
        *(f32x4*)(&sl[n * 68 + mt * 16 + q * 4]) = accS[mt];
      __syncthreads();
#pragma unroll
      for (int ks = 0; ks < 2; ++ks) {
        f32x4 s0 = *(const f32x4*)(&sl[n * 68 + ks * 32 + q * 8]);
        f32x4 s1 = *(const f32x4*)(&sl[n * 68 + ks * 32 + q * 8 + 4]);
#pragma unroll
        for (int j = 0; j < 4; ++j) {
          u16 hh, ll;
          split2(s0[j], hh, ll); Sbh[ks][j] = (short)hh; Sbl[ks][j] = (short)ll;
          split2(s1[j], hh, ll); Sbh[ks][j + 4] = (short)hh; Sbl[ks][j + 4] = (short)ll;
        }
      }
    }
  }
}

extern "C" void kernel_launch(void* const* d_in, const int* in_sizes, int n_in,
                              void* d_out, int out_size, void* d_ws, size_t ws_size,
                              hipStream_t stream) {
  const float* u  = (const float*)d_in[0];
  const float* A  = (const float*)d_in[1];
  const float* B  = (const float*)d_in[2];
  const float* C  = (const float*)d_in[3];
  const float* D  = (const float*)d_in[4];
  const float* ls = (const float*)d_in[5];
  float* ws  = (float*)d_ws;
  float* out = (float*)d_out;

  ssm_pre<<<dim3(1), dim3(1024), 0, stream>>>(A, B, C, D, ls, ws);
  ssm_scan_e<<<dim3(512), dim3(256), 0, stream>>>(ws, u);
  ssm_scan_sg<<<dim3(32), dim3(256), 0, stream>>>(ws);
  ssm_scan_main<<<dim3(512), dim3(256), 0, stream>>>(ws, u, out);
}